// Round 1
// baseline (7092.229 us; speedup 1.0000x reference)
//
#include <hip/hip_runtime.h>
#include <hip/hip_bf16.h>
#include <math.h>

#define BB 2
#define LL 1024
#define DIN_ 512
#define DM_ 1024
#define NL_ 4
#define EE 2048
#define NN 16
#define RR 64
#define KK 4

__device__ __forceinline__ float softplus_f(float x) {
    return fmaxf(x, 0.f) + log1pf(expf(-fabsf(x)));
}
__device__ __forceinline__ float silu_f(float x) {
    return x / (1.f + expf(-x));
}

// ---------------------------------------------------------------------------
// Tiled fp32 GEMM: C[m,n] = sum_k A[m*lda+k] * W[n*ldw+k]  (+epilogue)
// EPI: 0=none, 1=+bias, 2=softplus(+bias), 3=C+=acc (residual)
// Tile 128x128, BK=16, 256 threads, 8x8 micro-tile (2x2 blocks of 4).
// M must be a multiple of 128; N,K multiples of 4 (N guarded).
// ---------------------------------------------------------------------------
template <int EPI>
__global__ __launch_bounds__(256) void gemm_kernel(
    float* __restrict__ C, const float* __restrict__ A,
    const float* __restrict__ W, const float* __restrict__ bias,
    int M, int N, int K, int lda, int ldw, int ldc)
{
    __shared__ float As[16][128];
    __shared__ float Ws[16][128];

    const int tid = threadIdx.x;
    const int tx = tid & 15;   // n micro index
    const int ty = tid >> 4;   // m micro index
    const int m0 = blockIdx.y * 128;
    const int n0 = blockIdx.x * 128;

    float acc[8][8];
#pragma unroll
    for (int i = 0; i < 8; i++)
#pragma unroll
        for (int j = 0; j < 8; j++) acc[i][j] = 0.f;

    const float* Ablk = A + (size_t)m0 * lda;
    const float* Wblk = W + (size_t)n0 * ldw;

    for (int k0 = 0; k0 < K; k0 += 16) {
#pragma unroll
        for (int rep = 0; rep < 2; rep++) {
            int idx = rep * 256 + tid;
            int row = idx >> 2;
            int kq = idx & 3;
            float4 a = *(const float4*)(Ablk + (size_t)row * lda + k0 + kq * 4);
            As[kq * 4 + 0][row] = a.x;
            As[kq * 4 + 1][row] = a.y;
            As[kq * 4 + 2][row] = a.z;
            As[kq * 4 + 3][row] = a.w;
            float4 wv = make_float4(0.f, 0.f, 0.f, 0.f);
            if (n0 + row < N)
                wv = *(const float4*)(Wblk + (size_t)row * ldw + k0 + kq * 4);
            Ws[kq * 4 + 0][row] = wv.x;
            Ws[kq * 4 + 1][row] = wv.y;
            Ws[kq * 4 + 2][row] = wv.z;
            Ws[kq * 4 + 3][row] = wv.w;
        }
        __syncthreads();
#pragma unroll
        for (int k = 0; k < 16; k++) {
            float4 a0 = *(const float4*)&As[k][ty * 4];
            float4 a1 = *(const float4*)&As[k][64 + ty * 4];
            float4 b0 = *(const float4*)&Ws[k][tx * 4];
            float4 b1 = *(const float4*)&Ws[k][64 + tx * 4];
            float am[8] = {a0.x, a0.y, a0.z, a0.w, a1.x, a1.y, a1.z, a1.w};
            float bn[8] = {b0.x, b0.y, b0.z, b0.w, b1.x, b1.y, b1.z, b1.w};
#pragma unroll
            for (int i = 0; i < 8; i++)
#pragma unroll
                for (int j = 0; j < 8; j++)
                    acc[i][j] = fmaf(am[i], bn[j], acc[i][j]);
        }
        __syncthreads();
    }

#pragma unroll
    for (int bi = 0; bi < 2; bi++)
#pragma unroll
        for (int i = 0; i < 4; i++) {
            int m = m0 + bi * 64 + ty * 4 + i;
            float* crow = C + (size_t)m * ldc;
#pragma unroll
            for (int bj = 0; bj < 2; bj++) {
                int n = n0 + bj * 64 + tx * 4;
                if (n >= N) continue;
                float v[4];
                float4 old = make_float4(0.f, 0.f, 0.f, 0.f);
                if (EPI == 3) old = *(const float4*)(crow + n);
                float oldv[4] = {old.x, old.y, old.z, old.w};
#pragma unroll
                for (int j = 0; j < 4; j++) {
                    float t = acc[bi * 4 + i][bj * 4 + j];
                    if (EPI == 1 || EPI == 2) t += bias[n + j];
                    if (EPI == 2) t = softplus_f(t);
                    if (EPI == 3) t += oldv[j];
                    v[j] = t;
                }
                *(float4*)(crow + n) = make_float4(v[0], v[1], v[2], v[3]);
            }
        }
}

// ---------------------------------------------------------------------------
// Row LayerNorm over D=1024, one block (256 threads) per row.
// ---------------------------------------------------------------------------
__global__ __launch_bounds__(256) void layernorm_kernel(
    float* __restrict__ out, const float* __restrict__ in,
    const float* __restrict__ w, const float* __restrict__ b)
{
    const int row = blockIdx.x;
    const int tid = threadIdx.x;
    float4 v = ((const float4*)(in + (size_t)row * DM_))[tid];
    float s = v.x + v.y + v.z + v.w;
    float sq = v.x * v.x + v.y * v.y + v.z * v.z + v.w * v.w;
#pragma unroll
    for (int off = 32; off; off >>= 1) {
        s += __shfl_down(s, off);
        sq += __shfl_down(sq, off);
    }
    __shared__ float ls[4], lq[4];
    int wid = tid >> 6;
    if ((tid & 63) == 0) { ls[wid] = s; lq[wid] = sq; }
    __syncthreads();
    float S = ls[0] + ls[1] + ls[2] + ls[3];
    float Q = lq[0] + lq[1] + lq[2] + lq[3];
    float mean = S * (1.f / DM_);
    float var = Q * (1.f / DM_) - mean * mean;
    float inv = rsqrtf(var + 1e-5f);
    float4 wv = ((const float4*)w)[tid];
    float4 bv = ((const float4*)b)[tid];
    float4 o;
    o.x = (v.x - mean) * inv * wv.x + bv.x;
    o.y = (v.y - mean) * inv * wv.y + bv.y;
    o.z = (v.z - mean) * inv * wv.z + bv.z;
    o.w = (v.w - mean) * inv * wv.w + bv.w;
    ((float4*)(out + (size_t)row * DM_))[tid] = o;
}

// ---------------------------------------------------------------------------
// Causal depthwise conv (K=4) over the x-half of xz, + bias, + SiLU.
// grid (E/256, L, B)
// ---------------------------------------------------------------------------
__global__ __launch_bounds__(256) void conv_silu_kernel(
    float* __restrict__ xm, const float* __restrict__ xz,
    const float* __restrict__ cw, const float* __restrict__ cb)
{
    const int e = blockIdx.x * 256 + threadIdx.x;
    const int l = blockIdx.y;
    const int b = blockIdx.z;
    const float* X = xz + (size_t)b * LL * 2 * EE + e;
    float4 w4 = ((const float4*)cw)[e];
    float wk[4] = {w4.x, w4.y, w4.z, w4.w};
    float acc = cb[e];
#pragma unroll
    for (int k = 0; k < 4; k++) {
        int t = l + k - 3;
        if (t >= 0) acc = fmaf(wk[k], X[(size_t)t * 2 * EE], acc);
    }
    xm[((size_t)b * LL + l) * EE + e] = silu_f(acc);
}

// ---------------------------------------------------------------------------
// Selective scan. 16 lanes per (b,e) channel, one state n per lane.
// y[b,t,e] = (sum_n h*C + u*D) * silu(zg). grid = B*E/16 blocks of 256.
// ---------------------------------------------------------------------------
__global__ __launch_bounds__(256) void scan_kernel(
    float* __restrict__ y, const float* __restrict__ dt,
    const float* __restrict__ u, const float* __restrict__ xdb,
    const float* __restrict__ xz, const float* __restrict__ A_log,
    const float* __restrict__ Dp)
{
    const int tid = threadIdx.x;
    const int g = tid >> 4;
    const int n = tid & 15;
    const int ch = blockIdx.x * 16 + g;
    const int b = ch >> 11;       // E = 2048
    const int e = ch & (EE - 1);

    const float Ae = -expf(A_log[e * NN + n]);
    const float Dv = Dp[e];
    const float* dt_p = dt + (size_t)b * LL * EE + e;
    const float* u_p = u + (size_t)b * LL * EE + e;
    const float* bc_p = xdb + (size_t)b * LL * 96 + RR;   // B at +64, C at +80
    const float* zg_p = xz + (size_t)b * LL * 2 * EE + EE + e;
    float* y_p = y + (size_t)b * LL * EE + e;

    float hs = 0.f;
#pragma unroll 2
    for (int t = 0; t < LL; t++) {
        float dtv = dt_p[(size_t)t * EE];
        float uv = u_p[(size_t)t * EE];
        float Bv = bc_p[t * 96 + n];
        float Cv = bc_p[t * 96 + 16 + n];
        float da = expf(dtv * Ae);
        hs = fmaf(da, hs, (dtv * uv) * Bv);
        float p = hs * Cv;
        p += __shfl_xor(p, 8);
        p += __shfl_xor(p, 4);
        p += __shfl_xor(p, 2);
        p += __shfl_xor(p, 1);
        if (n == 0) {
            float zv = zg_p[(size_t)t * 2 * EE];
            y_p[(size_t)t * EE] = (p + uv * Dv) * silu_f(zv);
        }
    }
}

// ---------------------------------------------------------------------------
extern "C" void kernel_launch(void* const* d_in, const int* in_sizes, int n_in,
                              void* d_out, int out_size, void* d_ws, size_t ws_size,
                              hipStream_t stream)
{
    const float* x = (const float*)d_in[0];
    // d_in[1] = z (unused by reference)
    const float* ip_w = (const float*)d_in[2];
    const float* ip_b = (const float*)d_in[3];
    const float* ln_w = (const float*)d_in[4];
    const float* ln_b = (const float*)d_in[5];
    const float* inproj_w = (const float*)d_in[6];
    const float* conv_w = (const float*)d_in[7];
    const float* conv_b = (const float*)d_in[8];
    const float* xproj_w = (const float*)d_in[9];
    const float* dtproj_w = (const float*)d_in[10];
    const float* dtproj_b = (const float*)d_in[11];
    const float* A_log = (const float*)d_in[12];
    const float* Dp = (const float*)d_in[13];
    const float* outproj_w = (const float*)d_in[14];
    const float* fnorm_w = (const float*)d_in[15];
    const float* fnorm_b = (const float*)d_in[16];
    const float* op_w = (const float*)d_in[17];
    const float* op_b = (const float*)d_in[18];
    float* out = (float*)d_out;

    float* ws = (float*)d_ws;
    const size_t BL = (size_t)BB * LL;   // 2048
    float* h = ws;                        // BL*DM
    float* hn = h + BL * DM_;             // BL*DM
    float* xzb = hn + BL * DM_;           // BL*2E
    float* xm = xzb + BL * 2 * EE;        // BL*E
    float* xdb = xm + BL * EE;            // BL*96
    float* dtb = xdb + BL * 96;           // BL*E
    float* yb = dtb + BL * EE;            // BL*E

    dim3 blk(256);

    // h = x @ ip_w^T + ip_b   (M=2048, N=1024, K=512)
    gemm_kernel<1><<<dim3(DM_ / 128, BL / 128), blk, 0, stream>>>(
        h, x, ip_w, ip_b, BL, DM_, DIN_, DIN_, DIN_, DM_);

    for (int l = 0; l < NL_; l++) {
        layernorm_kernel<<<dim3(BL), blk, 0, stream>>>(hn, h, ln_w + l * DM_, ln_b + l * DM_);
        // xz = hn @ inproj^T   (N=4096, K=1024)
        gemm_kernel<0><<<dim3(2 * EE / 128, BL / 128), blk, 0, stream>>>(
            xzb, hn, inproj_w + (size_t)l * 2 * EE * DM_, nullptr,
            BL, 2 * EE, DM_, DM_, DM_, 2 * EE);
        conv_silu_kernel<<<dim3(EE / 256, LL, BB), blk, 0, stream>>>(
            xm, xzb, conv_w + l * EE * KK, conv_b + l * EE);
        // x_dbl = xm @ xproj^T (N=96, K=2048)
        gemm_kernel<0><<<dim3(1, BL / 128), blk, 0, stream>>>(
            xdb, xm, xproj_w + (size_t)l * 96 * EE, nullptr,
            BL, 96, EE, EE, EE, 96);
        // dt = softplus(x_dbl[:, :R] @ dtproj^T + dtproj_b) (N=2048, K=64)
        gemm_kernel<2><<<dim3(EE / 128, BL / 128), blk, 0, stream>>>(
            dtb, xdb, dtproj_w + (size_t)l * EE * RR, dtproj_b + l * EE,
            BL, EE, RR, 96, RR, EE);
        scan_kernel<<<dim3(BB * EE / 16), blk, 0, stream>>>(
            yb, dtb, xm, xdb, xzb, A_log + l * EE * NN, Dp + l * EE);
        // h += y @ outproj^T (N=1024, K=2048)
        gemm_kernel<3><<<dim3(DM_ / 128, BL / 128), blk, 0, stream>>>(
            h, yb, outproj_w + (size_t)l * DM_ * EE, nullptr,
            BL, DM_, EE, EE, EE, DM_);
    }

    layernorm_kernel<<<dim3(BL), blk, 0, stream>>>(hn, h, fnorm_w, fnorm_b);
    // out = hn @ op_w^T + op_b (N=512, K=1024)
    gemm_kernel<1><<<dim3(DIN_ / 128, BL / 128), blk, 0, stream>>>(
        out, hn, op_w, op_b, BL, DIN_, DM_, DM_, DM_, DIN_);
}

// Round 2
// 3889.793 us; speedup vs baseline: 1.8233x; 1.8233x over previous
//
#include <hip/hip_runtime.h>
#include <hip/hip_bf16.h>
#include <math.h>

#define BB 2
#define LL 1024
#define DIN_ 512
#define DM_ 1024
#define NL_ 4
#define EE 2048
#define NN 16
#define RR 64
#define KK 4

__device__ __forceinline__ float softplus_f(float x) {
    return fmaxf(x, 0.f) + log1pf(expf(-fabsf(x)));
}
__device__ __forceinline__ float silu_f(float x) {
    return x / (1.f + expf(-x));
}

// ---------------------------------------------------------------------------
// Tiled fp32 GEMM: C[m,n] = sum_k A[m*lda+k] * W[n*ldw+k]  (+epilogue)
// EPI: 0=none, 1=+bias, 2=softplus(+bias), 3=C+=acc (residual),
//      4=split-K atomicAdd (K param = chunk size; blockIdx.z picks chunk)
// Tile 128x128, BK=16, 256 threads, 8x8 micro-tile.
// ---------------------------------------------------------------------------
template <int EPI>
__global__ __launch_bounds__(256) void gemm_kernel(
    float* __restrict__ C, const float* __restrict__ A,
    const float* __restrict__ W, const float* __restrict__ bias,
    int M, int N, int K, int lda, int ldw, int ldc)
{
    __shared__ float As[16][128];
    __shared__ float Ws[16][128];

    const int tid = threadIdx.x;
    const int tx = tid & 15;   // n micro index
    const int ty = tid >> 4;   // m micro index
    const int m0 = blockIdx.y * 128;
    const int n0 = blockIdx.x * 128;

    float acc[8][8];
#pragma unroll
    for (int i = 0; i < 8; i++)
#pragma unroll
        for (int j = 0; j < 8; j++) acc[i][j] = 0.f;

    const float* Ablk = A + (size_t)m0 * lda;
    const float* Wblk = W + (size_t)n0 * ldw;
    if (EPI == 4) {   // split-K: offset along k by blockIdx.z * K
        Ablk += (size_t)blockIdx.z * K;
        Wblk += (size_t)blockIdx.z * K;
    }

    for (int k0 = 0; k0 < K; k0 += 16) {
#pragma unroll
        for (int rep = 0; rep < 2; rep++) {
            int idx = rep * 256 + tid;
            int row = idx >> 2;
            int kq = idx & 3;
            float4 a = *(const float4*)(Ablk + (size_t)row * lda + k0 + kq * 4);
            As[kq * 4 + 0][row] = a.x;
            As[kq * 4 + 1][row] = a.y;
            As[kq * 4 + 2][row] = a.z;
            As[kq * 4 + 3][row] = a.w;
            float4 wv = make_float4(0.f, 0.f, 0.f, 0.f);
            if (n0 + row < N)
                wv = *(const float4*)(Wblk + (size_t)row * ldw + k0 + kq * 4);
            Ws[kq * 4 + 0][row] = wv.x;
            Ws[kq * 4 + 1][row] = wv.y;
            Ws[kq * 4 + 2][row] = wv.z;
            Ws[kq * 4 + 3][row] = wv.w;
        }
        __syncthreads();
#pragma unroll
        for (int k = 0; k < 16; k++) {
            float4 a0 = *(const float4*)&As[k][ty * 4];
            float4 a1 = *(const float4*)&As[k][64 + ty * 4];
            float4 b0 = *(const float4*)&Ws[k][tx * 4];
            float4 b1 = *(const float4*)&Ws[k][64 + tx * 4];
            float am[8] = {a0.x, a0.y, a0.z, a0.w, a1.x, a1.y, a1.z, a1.w};
            float bn[8] = {b0.x, b0.y, b0.z, b0.w, b1.x, b1.y, b1.z, b1.w};
#pragma unroll
            for (int i = 0; i < 8; i++)
#pragma unroll
                for (int j = 0; j < 8; j++)
                    acc[i][j] = fmaf(am[i], bn[j], acc[i][j]);
        }
        __syncthreads();
    }

#pragma unroll
    for (int bi = 0; bi < 2; bi++)
#pragma unroll
        for (int i = 0; i < 4; i++) {
            int m = m0 + bi * 64 + ty * 4 + i;
            float* crow = C + (size_t)m * ldc;
#pragma unroll
            for (int bj = 0; bj < 2; bj++) {
                int n = n0 + bj * 64 + tx * 4;
                if (n >= N) continue;
                if (EPI == 4) {
#pragma unroll
                    for (int j = 0; j < 4; j++)
                        atomicAdd(crow + n + j, acc[bi * 4 + i][bj * 4 + j]);
                    continue;
                }
                float v[4];
                float4 old = make_float4(0.f, 0.f, 0.f, 0.f);
                if (EPI == 3) old = *(const float4*)(crow + n);
                float oldv[4] = {old.x, old.y, old.z, old.w};
#pragma unroll
                for (int j = 0; j < 4; j++) {
                    float t = acc[bi * 4 + i][bj * 4 + j];
                    if (EPI == 1 || EPI == 2) t += bias[n + j];
                    if (EPI == 2) t = softplus_f(t);
                    if (EPI == 3) t += oldv[j];
                    v[j] = t;
                }
                *(float4*)(crow + n) = make_float4(v[0], v[1], v[2], v[3]);
            }
        }
}

__global__ __launch_bounds__(256) void zero_kernel(float* __restrict__ p, int n4)
{
    int i = blockIdx.x * 256 + threadIdx.x;
    if (i < n4) ((float4*)p)[i] = make_float4(0.f, 0.f, 0.f, 0.f);
}

// ---------------------------------------------------------------------------
// Row LayerNorm over D=1024, one block (256 threads) per row.
// ---------------------------------------------------------------------------
__global__ __launch_bounds__(256) void layernorm_kernel(
    float* __restrict__ out, const float* __restrict__ in,
    const float* __restrict__ w, const float* __restrict__ b)
{
    const int row = blockIdx.x;
    const int tid = threadIdx.x;
    float4 v = ((const float4*)(in + (size_t)row * DM_))[tid];
    float s = v.x + v.y + v.z + v.w;
    float sq = v.x * v.x + v.y * v.y + v.z * v.z + v.w * v.w;
#pragma unroll
    for (int off = 32; off; off >>= 1) {
        s += __shfl_down(s, off);
        sq += __shfl_down(sq, off);
    }
    __shared__ float ls[4], lq[4];
    int wid = tid >> 6;
    if ((tid & 63) == 0) { ls[wid] = s; lq[wid] = sq; }
    __syncthreads();
    float S = ls[0] + ls[1] + ls[2] + ls[3];
    float Q = lq[0] + lq[1] + lq[2] + lq[3];
    float mean = S * (1.f / DM_);
    float var = Q * (1.f / DM_) - mean * mean;
    float inv = rsqrtf(var + 1e-5f);
    float4 wv = ((const float4*)w)[tid];
    float4 bv = ((const float4*)b)[tid];
    float4 o;
    o.x = (v.x - mean) * inv * wv.x + bv.x;
    o.y = (v.y - mean) * inv * wv.y + bv.y;
    o.z = (v.z - mean) * inv * wv.z + bv.z;
    o.w = (v.w - mean) * inv * wv.w + bv.w;
    ((float4*)(out + (size_t)row * DM_))[tid] = o;
}

// ---------------------------------------------------------------------------
// Causal depthwise conv (K=4) over the x-half of xz, + bias, + SiLU.
// ---------------------------------------------------------------------------
__global__ __launch_bounds__(256) void conv_silu_kernel(
    float* __restrict__ xm, const float* __restrict__ xz,
    const float* __restrict__ cw, const float* __restrict__ cb)
{
    const int e = blockIdx.x * 256 + threadIdx.x;
    const int l = blockIdx.y;
    const int b = blockIdx.z;
    const float* X = xz + (size_t)b * LL * 2 * EE + e;
    float4 w4 = ((const float4*)cw)[e];
    float wk[4] = {w4.x, w4.y, w4.z, w4.w};
    float acc = cb[e];
#pragma unroll
    for (int k = 0; k < 4; k++) {
        int t = l + k - 3;
        if (t >= 0) acc = fmaf(wk[k], X[(size_t)t * 2 * EE], acc);
    }
    xm[((size_t)b * LL + l) * EE + e] = silu_f(acc);
}

// ---------------------------------------------------------------------------
// Chunked selective scan. One block per (b,e) channel; 256 threads =
// 16 chunks (g) x 16 states (n). L=1024 -> 16 chunks of 64.
// Phase 1: per-chunk affine summary (P = prod dA, S = local scan end).
// LDS combine (15 serial fmas) -> per-chunk h-init.
// Phase 2: replay chunk with correct init, emit y (shfl-reduce over n).
// ---------------------------------------------------------------------------
__global__ __launch_bounds__(256) void scan_kernel(
    float* __restrict__ y, const float* __restrict__ dt,
    const float* __restrict__ u, const float* __restrict__ xdb,
    const float* __restrict__ xz, const float* __restrict__ A_log,
    const float* __restrict__ Dp)
{
    const int tid = threadIdx.x;
    const int g = tid >> 4;       // chunk index 0..15
    const int n = tid & 15;       // state index
    const int ch = blockIdx.x;    // b*E + e
    const int b = ch >> 11;       // E = 2048
    const int e = ch & (EE - 1);

    const float Ae = -expf(A_log[e * NN + n]);
    const float Dv = Dp[e];
    const float* dt_p = dt + (size_t)b * LL * EE + e;
    const float* u_p = u + (size_t)b * LL * EE + e;
    const float* bc_p = xdb + (size_t)b * LL * 96 + RR;   // B at +64, C at +80
    const float* zg_p = xz + (size_t)b * LL * 2 * EE + EE + e;
    float* y_p = y + (size_t)b * LL * EE + e;

    const int t0 = g * 64;

    // Phase 1: local affine summary with h_init = 0
    float P = 1.f, S = 0.f;
#pragma unroll 4
    for (int i = 0; i < 64; i++) {
        int t = t0 + i;
        float dtv = dt_p[(size_t)t * EE];
        float uv = u_p[(size_t)t * EE];
        float Bv = bc_p[t * 96 + n];
        float da = expf(dtv * Ae);
        S = fmaf(da, S, (dtv * uv) * Bv);
        P *= da;
    }

    __shared__ float Ps[16][17], Ss[16][17], H0[16][17];
    Ps[g][n] = P;
    Ss[g][n] = S;
    __syncthreads();
    if (g == 0) {
        float h = 0.f;
        H0[0][n] = 0.f;
        for (int q = 1; q < 16; q++) {
            h = fmaf(Ps[q - 1][n], h, Ss[q - 1][n]);
            H0[q][n] = h;
        }
    }
    __syncthreads();
    float hs = H0[g][n];

    // Phase 2: replay with correct h_init, emit outputs (loads are L2-warm)
#pragma unroll 4
    for (int i = 0; i < 64; i++) {
        int t = t0 + i;
        float dtv = dt_p[(size_t)t * EE];
        float uv = u_p[(size_t)t * EE];
        float Bv = bc_p[t * 96 + n];
        float Cv = bc_p[t * 96 + 16 + n];
        float da = expf(dtv * Ae);
        hs = fmaf(da, hs, (dtv * uv) * Bv);
        float p = hs * Cv;
        p += __shfl_xor(p, 8);
        p += __shfl_xor(p, 4);
        p += __shfl_xor(p, 2);
        p += __shfl_xor(p, 1);
        if (n == 0) {
            float zv = zg_p[(size_t)t * 2 * EE];
            y_p[(size_t)t * EE] = (p + uv * Dv) * silu_f(zv);
        }
    }
}

// ---------------------------------------------------------------------------
extern "C" void kernel_launch(void* const* d_in, const int* in_sizes, int n_in,
                              void* d_out, int out_size, void* d_ws, size_t ws_size,
                              hipStream_t stream)
{
    const float* x = (const float*)d_in[0];
    const float* ip_w = (const float*)d_in[2];
    const float* ip_b = (const float*)d_in[3];
    const float* ln_w = (const float*)d_in[4];
    const float* ln_b = (const float*)d_in[5];
    const float* inproj_w = (const float*)d_in[6];
    const float* conv_w = (const float*)d_in[7];
    const float* conv_b = (const float*)d_in[8];
    const float* xproj_w = (const float*)d_in[9];
    const float* dtproj_w = (const float*)d_in[10];
    const float* dtproj_b = (const float*)d_in[11];
    const float* A_log = (const float*)d_in[12];
    const float* Dp = (const float*)d_in[13];
    const float* outproj_w = (const float*)d_in[14];
    const float* fnorm_w = (const float*)d_in[15];
    const float* fnorm_b = (const float*)d_in[16];
    const float* op_w = (const float*)d_in[17];
    const float* op_b = (const float*)d_in[18];
    float* out = (float*)d_out;

    float* ws = (float*)d_ws;
    const size_t BL = (size_t)BB * LL;   // 2048
    float* h = ws;                        // BL*DM
    float* hn = h + BL * DM_;             // BL*DM
    float* xzb = hn + BL * DM_;           // BL*2E
    float* xm = xzb + BL * 2 * EE;        // BL*E
    float* xdb = xm + BL * EE;            // BL*96
    float* dtb = xdb + BL * 96;           // BL*E
    float* yb = dtb + BL * EE;            // BL*E

    dim3 blk(256);

    // h = x @ ip_w^T + ip_b   (M=2048, N=1024, K=512)
    gemm_kernel<1><<<dim3(DM_ / 128, BL / 128), blk, 0, stream>>>(
        h, x, ip_w, ip_b, BL, DM_, DIN_, DIN_, DIN_, DM_);

    for (int l = 0; l < NL_; l++) {
        layernorm_kernel<<<dim3(BL), blk, 0, stream>>>(hn, h, ln_w + l * DM_, ln_b + l * DM_);
        // xz = hn @ inproj^T   (N=4096, K=1024)
        gemm_kernel<0><<<dim3(2 * EE / 128, BL / 128), blk, 0, stream>>>(
            xzb, hn, inproj_w + (size_t)l * 2 * EE * DM_, nullptr,
            BL, 2 * EE, DM_, DM_, DM_, 2 * EE);
        conv_silu_kernel<<<dim3(EE / 256, LL, BB), blk, 0, stream>>>(
            xm, xzb, conv_w + l * EE * KK, conv_b + l * EE);
        // x_dbl = xm @ xproj^T (N=96, K=2048) — split-K x16, atomicAdd epilogue
        zero_kernel<<<dim3((BL * 96 / 4 + 255) / 256), blk, 0, stream>>>(xdb, BL * 96 / 4);
        gemm_kernel<4><<<dim3(1, BL / 128, 16), blk, 0, stream>>>(
            xdb, xm, xproj_w + (size_t)l * 96 * EE, nullptr,
            BL, 96, EE / 16, EE, EE, 96);
        // dt = softplus(x_dbl[:, :R] @ dtproj^T + dtproj_b) (N=2048, K=64)
        gemm_kernel<2><<<dim3(EE / 128, BL / 128), blk, 0, stream>>>(
            dtb, xdb, dtproj_w + (size_t)l * EE * RR, dtproj_b + l * EE,
            BL, EE, RR, 96, RR, EE);
        scan_kernel<<<dim3(BB * EE), blk, 0, stream>>>(
            yb, dtb, xm, xdb, xzb, A_log + l * EE * NN, Dp + l * EE);
        // h += y @ outproj^T (N=1024, K=2048)
        gemm_kernel<3><<<dim3(DM_ / 128, BL / 128), blk, 0, stream>>>(
            h, yb, outproj_w + (size_t)l * DM_ * EE, nullptr,
            BL, DM_, EE, EE, EE, DM_);
    }

    layernorm_kernel<<<dim3(BL), blk, 0, stream>>>(hn, h, fnorm_w, fnorm_b);
    // out = hn @ op_w^T + op_b (N=512, K=1024)
    gemm_kernel<1><<<dim3(DIN_ / 128, BL / 128), blk, 0, stream>>>(
        out, hn, op_w, op_b, BL, DIN_, DM_, DM_, DM_, DIN_);
}

// Round 3
// 1654.877 us; speedup vs baseline: 4.2857x; 2.3505x over previous
//
#include <hip/hip_runtime.h>
#include <math.h>

#define BB 2
#define LL 1024
#define DIN_ 512
#define DM_ 1024
#define NL_ 4
#define EE 2048
#define NN 16
#define RR 64
#define KK 4

typedef unsigned short ushort_t;
typedef unsigned int uint_t;

using frag_ab = __attribute__((ext_vector_type(8))) short;
using frag_cd = __attribute__((ext_vector_type(4))) float;

__device__ __forceinline__ float softplus_f(float x) {
    return fmaxf(x, 0.f) + log1pf(expf(-fabsf(x)));
}
__device__ __forceinline__ float silu_f(float x) {
    return x / (1.f + expf(-x));
}
__device__ __forceinline__ float bf2f(ushort_t x) {
    return __uint_as_float((uint_t)x << 16);
}
__device__ __forceinline__ ushort_t f2bf(float x) {
    uint_t u = __float_as_uint(x);
    uint_t r = (u + 0x7fffu + ((u >> 16) & 1u)) >> 16;   // RNE
    return (ushort_t)r;
}
__device__ __forceinline__ void gload_lds16(const void* g, void* l) {
    __builtin_amdgcn_global_load_lds(
        (const __attribute__((address_space(1))) void*)g,
        (__attribute__((address_space(3))) void*)l, 16, 0, 0);
}

// ---------------------------------------------------------------------------
// fp32 -> bf16 convert (n multiple of 4)
// ---------------------------------------------------------------------------
__global__ __launch_bounds__(256) void cvt_bf16_kernel(
    ushort_t* __restrict__ o, const float* __restrict__ in, int n4)
{
    int i = blockIdx.x * 256 + threadIdx.x;
    if (i >= n4) return;
    float4 v = ((const float4*)in)[i];
    ushort4 u;
    u.x = f2bf(v.x); u.y = f2bf(v.y); u.z = f2bf(v.z); u.w = f2bf(v.w);
    ((ushort4*)o)[i] = u;
}

__global__ __launch_bounds__(256) void zero_kernel(float* __restrict__ p, int n4)
{
    int i = blockIdx.x * 256 + threadIdx.x;
    if (i < n4) ((float4*)p)[i] = make_float4(0.f, 0.f, 0.f, 0.f);
}

// ---------------------------------------------------------------------------
// bf16 MFMA GEMM: C[m,n] = sum_k A[m,k]*W[n,k]  (both K-contiguous, bf16)
// Tile: M=128 x N=NT*16, BK=32. 256 threads = 2x2 waves; wave = 4 m-tiles x
// NT/2 n-tiles of 16x16x32 MFMA. LDS holds fragment-ordered tiles: each
// 16(row)x32(k) fragment is one contiguous 1024B block in MFMA lane order,
// so global_load_lds (wave-uniform base + lane*16) stages it directly and
// ds_read_b128 at frag_base + lane*16 is conflict-free.
// EPI: 0 none, 1 +bias, 2 softplus(+bias), 3 C+=acc, 4 atomicAdd (split-K
// via blockIdx.z, K = chunk size). OUTBF: write bf16 instead of fp32.
// ---------------------------------------------------------------------------
template <int EPI, int NT, int OUTBF>
__global__ __launch_bounds__(256) void mgemm_kernel(
    void* __restrict__ Cp, const ushort_t* __restrict__ A,
    const ushort_t* __restrict__ W, const float* __restrict__ bias,
    int N, int K, int lda, int ldw, int ldc)
{
    __shared__ __attribute__((aligned(16))) ushort_t As[8 * 512];
    __shared__ __attribute__((aligned(16))) ushort_t Bs[NT * 512];

    const int tid = threadIdx.x;
    const int w = tid >> 6;
    const int lane = tid & 63;
    const int r = lane & 15;
    const int q = lane >> 4;
    const int m0 = blockIdx.y * 128;
    const int n0 = blockIdx.x * (NT * 16);
    const int wm = w >> 1;          // 0..1
    const int wn = w & 1;           // 0..1
    const int NWT = NT / 2;         // n-tiles per wave

    frag_cd acc[4][NWT];
#pragma unroll
    for (int i = 0; i < 4; i++)
#pragma unroll
        for (int j = 0; j < NWT; j++)
#pragma unroll
            for (int t = 0; t < 4; t++) acc[i][j][t] = 0.f;

    size_t koff = (EPI == 4) ? (size_t)blockIdx.z * K : 0;
    const ushort_t* Ab = A + (size_t)m0 * lda + koff;
    const ushort_t* Wb = W + (size_t)n0 * ldw + koff;

    const int NFRAG = 8 + NT;
    for (int k0 = 0; k0 < K; k0 += 32) {
        // ---- stage: each wave loads its share of the 16-row x 32-k frags
        for (int F = w; F < NFRAG; F += 4) {
            if (F < 8) {
                const ushort_t* g = Ab + (size_t)(F * 16 + r) * lda + k0 + q * 8;
                gload_lds16(g, As + F * 512);
            } else {
                int nt = F - 8;
                if (n0 + nt * 16 + r < N) {
                    const ushort_t* g = Wb + (size_t)(nt * 16 + r) * ldw + k0 + q * 8;
                    gload_lds16(g, Bs + nt * 512);
                }
            }
        }
        __syncthreads();
        // ---- compute
        frag_ab af[4], bf[NWT];
#pragma unroll
        for (int i = 0; i < 4; i++)
            af[i] = *(const frag_ab*)(As + (wm * 4 + i) * 512 + lane * 8);
#pragma unroll
        for (int j = 0; j < NWT; j++)
            bf[j] = *(const frag_ab*)(Bs + (wn * NWT + j) * 512 + lane * 8);
#pragma unroll
        for (int i = 0; i < 4; i++)
#pragma unroll
            for (int j = 0; j < NWT; j++)
                acc[i][j] = __builtin_amdgcn_mfma_f32_16x16x32_bf16(
                    af[i], bf[j], acc[i][j], 0, 0, 0);
        __syncthreads();
    }

    // ---- epilogue: C/D layout col=lane&15, row=quad*4+reg
    float* Cf = (float*)Cp;
    ushort_t* Cb = (ushort_t*)Cp;
#pragma unroll
    for (int i = 0; i < 4; i++) {
        int mrow = m0 + (wm * 4 + i) * 16 + q * 4;
#pragma unroll
        for (int j = 0; j < NWT; j++) {
            int col = n0 + (wn * NWT + j) * 16 + r;
            if (col >= N) continue;
            float bv = (EPI == 1 || EPI == 2) ? bias[col] : 0.f;
#pragma unroll
            for (int t = 0; t < 4; t++) {
                float v = acc[i][j][t];
                size_t idx = (size_t)(mrow + t) * ldc + col;
                if (EPI == 4) { atomicAdd(Cf + idx, v); continue; }
                if (EPI == 1) v += bv;
                if (EPI == 2) v = softplus_f(v + bv);
                if (EPI == 3) v += Cf[idx];
                if (OUTBF) Cb[idx] = f2bf(v);
                else       Cf[idx] = v;
            }
        }
    }
}

// ---------------------------------------------------------------------------
// Row LayerNorm over D=1024 (fp32 in), bf16 out. One block per row.
// ---------------------------------------------------------------------------
__global__ __launch_bounds__(256) void layernorm_kernel(
    ushort_t* __restrict__ out, const float* __restrict__ in,
    const float* __restrict__ w, const float* __restrict__ b)
{
    const int row = blockIdx.x;
    const int tid = threadIdx.x;
    float4 v = ((const float4*)(in + (size_t)row * DM_))[tid];
    float s = v.x + v.y + v.z + v.w;
    float sq = v.x * v.x + v.y * v.y + v.z * v.z + v.w * v.w;
#pragma unroll
    for (int off = 32; off; off >>= 1) {
        s += __shfl_down(s, off);
        sq += __shfl_down(sq, off);
    }
    __shared__ float ls[4], lq[4];
    int wid = tid >> 6;
    if ((tid & 63) == 0) { ls[wid] = s; lq[wid] = sq; }
    __syncthreads();
    float S = ls[0] + ls[1] + ls[2] + ls[3];
    float Q = lq[0] + lq[1] + lq[2] + lq[3];
    float mean = S * (1.f / DM_);
    float var = Q * (1.f / DM_) - mean * mean;
    float inv = rsqrtf(var + 1e-5f);
    float4 wv = ((const float4*)w)[tid];
    float4 bv = ((const float4*)b)[tid];
    ushort4 o;
    o.x = f2bf((v.x - mean) * inv * wv.x + bv.x);
    o.y = f2bf((v.y - mean) * inv * wv.y + bv.y);
    o.z = f2bf((v.z - mean) * inv * wv.z + bv.z);
    o.w = f2bf((v.w - mean) * inv * wv.w + bv.w);
    ((ushort4*)(out + (size_t)row * DM_))[tid] = o;
}

// ---------------------------------------------------------------------------
// Causal depthwise conv (K=4) on bf16 xz (x-half), + bias, + SiLU -> bf16 xm
// ---------------------------------------------------------------------------
__global__ __launch_bounds__(256) void conv_silu_kernel(
    ushort_t* __restrict__ xm, const ushort_t* __restrict__ xz,
    const float* __restrict__ cw, const float* __restrict__ cb)
{
    const int e = blockIdx.x * 256 + threadIdx.x;
    const int l = blockIdx.y;
    const int b = blockIdx.z;
    const ushort_t* X = xz + (size_t)b * LL * 2 * EE + e;
    float4 w4 = ((const float4*)cw)[e];
    float wk[4] = {w4.x, w4.y, w4.z, w4.w};
    float acc = cb[e];
#pragma unroll
    for (int k = 0; k < 4; k++) {
        int t = l + k - 3;
        if (t >= 0) acc = fmaf(wk[k], bf2f(X[(size_t)t * 2 * EE]), acc);
    }
    xm[((size_t)b * LL + l) * EE + e] = f2bf(silu_f(acc));
}

// ---------------------------------------------------------------------------
// Chunked selective scan (verified round 2). u/zg bf16, dt/B/C fp32, y bf16.
// ---------------------------------------------------------------------------
__global__ __launch_bounds__(256) void scan_kernel(
    ushort_t* __restrict__ y, const float* __restrict__ dt,
    const ushort_t* __restrict__ u, const float* __restrict__ xdb,
    const ushort_t* __restrict__ xz, const float* __restrict__ A_log,
    const float* __restrict__ Dp)
{
    const int tid = threadIdx.x;
    const int g = tid >> 4;
    const int n = tid & 15;
    const int ch = blockIdx.x;
    const int b = ch >> 11;
    const int e = ch & (EE - 1);

    const float Ae = -expf(A_log[e * NN + n]);
    const float Dv = Dp[e];
    const float* dt_p = dt + (size_t)b * LL * EE + e;
    const ushort_t* u_p = u + (size_t)b * LL * EE + e;
    const float* bc_p = xdb + (size_t)b * LL * 96 + RR;
    const ushort_t* zg_p = xz + (size_t)b * LL * 2 * EE + EE + e;
    ushort_t* y_p = y + (size_t)b * LL * EE + e;

    const int t0 = g * 64;

    float P = 1.f, S = 0.f;
#pragma unroll 4
    for (int i = 0; i < 64; i++) {
        int t = t0 + i;
        float dtv = dt_p[(size_t)t * EE];
        float uv = bf2f(u_p[(size_t)t * EE]);
        float Bv = bc_p[t * 96 + n];
        float da = expf(dtv * Ae);
        S = fmaf(da, S, (dtv * uv) * Bv);
        P *= da;
    }

    __shared__ float Ps[16][17], Ss[16][17], H0[16][17];
    Ps[g][n] = P;
    Ss[g][n] = S;
    __syncthreads();
    if (g == 0) {
        float h = 0.f;
        H0[0][n] = 0.f;
        for (int qq = 1; qq < 16; qq++) {
            h = fmaf(Ps[qq - 1][n], h, Ss[qq - 1][n]);
            H0[qq][n] = h;
        }
    }
    __syncthreads();
    float hs = H0[g][n];

#pragma unroll 4
    for (int i = 0; i < 64; i++) {
        int t = t0 + i;
        float dtv = dt_p[(size_t)t * EE];
        float uv = bf2f(u_p[(size_t)t * EE]);
        float Bv = bc_p[t * 96 + n];
        float Cv = bc_p[t * 96 + 16 + n];
        float da = expf(dtv * Ae);
        hs = fmaf(da, hs, (dtv * uv) * Bv);
        float p = hs * Cv;
        p += __shfl_xor(p, 8);
        p += __shfl_xor(p, 4);
        p += __shfl_xor(p, 2);
        p += __shfl_xor(p, 1);
        if (n == 0) {
            float zv = bf2f(zg_p[(size_t)t * 2 * EE]);
            y_p[(size_t)t * EE] = f2bf((p + uv * Dv) * silu_f(zv));
        }
    }
}

// ---------------------------------------------------------------------------
extern "C" void kernel_launch(void* const* d_in, const int* in_sizes, int n_in,
                              void* d_out, int out_size, void* d_ws, size_t ws_size,
                              hipStream_t stream)
{
    const float* x = (const float*)d_in[0];
    const float* ip_w = (const float*)d_in[2];
    const float* ip_b = (const float*)d_in[3];
    const float* ln_w = (const float*)d_in[4];
    const float* ln_b = (const float*)d_in[5];
    const float* inproj_w = (const float*)d_in[6];
    const float* conv_w = (const float*)d_in[7];
    const float* conv_b = (const float*)d_in[8];
    const float* xproj_w = (const float*)d_in[9];
    const float* dtproj_w = (const float*)d_in[10];
    const float* dtproj_b = (const float*)d_in[11];
    const float* A_log = (const float*)d_in[12];
    const float* Dp = (const float*)d_in[13];
    const float* outproj_w = (const float*)d_in[14];
    const float* fnorm_w = (const float*)d_in[15];
    const float* fnorm_b = (const float*)d_in[16];
    const float* op_w = (const float*)d_in[17];
    const float* op_b = (const float*)d_in[18];
    float* out = (float*)d_out;

    const size_t BL = (size_t)BB * LL;   // 2048

    // ---- workspace layout: fp32 region then bf16 region
    float* fp = (float*)d_ws;
    float* h = fp;           fp += BL * DM_;          // 2M
    float* xdb = fp;         fp += BL * 96;           // 196K
    float* dtb = fp;         fp += BL * EE;           // 4M
    ushort_t* us = (ushort_t*)fp;
    ushort_t* xb = us;       us += BL * DIN_;         // 1M
    ushort_t* hnb = us;      us += BL * DM_;          // 2M
    ushort_t* xzb = us;      us += BL * 2 * EE;       // 8M
    ushort_t* xm = us;       us += BL * EE;           // 4M
    ushort_t* xdbb = us;     us += BL * 96;           // 196K
    ushort_t* yb = us;       us += BL * EE;           // 4M
    ushort_t* ipwb = us;     us += (size_t)DM_ * DIN_;
    ushort_t* inprojb = us;  us += (size_t)NL_ * 2 * EE * DM_;
    ushort_t* xprojb = us;   us += (size_t)NL_ * 96 * EE;
    ushort_t* dtprojb = us;  us += (size_t)NL_ * EE * RR;
    ushort_t* outprojb = us; us += (size_t)NL_ * DM_ * EE;
    ushort_t* opwb = us;     us += (size_t)DIN_ * DM_;

    dim3 blk(256);
    auto cvt = [&](ushort_t* dst, const float* src, size_t n) {
        int n4 = (int)(n / 4);
        cvt_bf16_kernel<<<dim3((n4 + 255) / 256), blk, 0, stream>>>(dst, src, n4);
    };

    // ---- weight + input conversions
    cvt(xb, x, BL * DIN_);
    cvt(ipwb, ip_w, (size_t)DM_ * DIN_);
    cvt(inprojb, inproj_w, (size_t)NL_ * 2 * EE * DM_);
    cvt(xprojb, xproj_w, (size_t)NL_ * 96 * EE);
    cvt(dtprojb, dtproj_w, (size_t)NL_ * EE * RR);
    cvt(outprojb, outproj_w, (size_t)NL_ * DM_ * EE);
    cvt(opwb, op_w, (size_t)DIN_ * DM_);

    // ---- h = x @ ip_w^T + ip_b   (N=1024, K=512) : NT=4 -> grid 16x16
    mgemm_kernel<1, 4, 0><<<dim3(DM_ / 64, BL / 128), blk, 0, stream>>>(
        h, xb, ipwb, ip_b, DM_, DIN_, DIN_, DIN_, DM_);

    for (int l = 0; l < NL_; l++) {
        layernorm_kernel<<<dim3(BL), blk, 0, stream>>>(hnb, h, ln_w + l * DM_, ln_b + l * DM_);
        // xz = hn @ inproj^T (N=4096, K=1024), bf16 out : grid 32x16
        mgemm_kernel<0, 8, 1><<<dim3(2 * EE / 128, BL / 128), blk, 0, stream>>>(
            xzb, hnb, inprojb + (size_t)l * 2 * EE * DM_, nullptr,
            2 * EE, DM_, DM_, DM_, 2 * EE);
        conv_silu_kernel<<<dim3(EE / 256, LL, BB), blk, 0, stream>>>(
            xm, xzb, conv_w + l * EE * KK, conv_b + l * EE);
        // x_dbl = xm @ xproj^T (N=96, K=2048): split-K x16, atomicAdd
        zero_kernel<<<dim3((int)(BL * 96 / 4 + 255) / 256), blk, 0, stream>>>(xdb, (int)(BL * 96 / 4));
        mgemm_kernel<4, 8, 0><<<dim3(1, BL / 128, 16), blk, 0, stream>>>(
            xdb, xm, xprojb + (size_t)l * 96 * EE, nullptr,
            96, EE / 16, EE, EE, 96);
        cvt(xdbb, xdb, BL * 96);
        // dt = softplus(x_dbl[:, :R] @ dtproj^T + b) (N=2048, K=64) : grid 16x16
        mgemm_kernel<2, 8, 0><<<dim3(EE / 128, BL / 128), blk, 0, stream>>>(
            dtb, xdbb, dtprojb + (size_t)l * EE * RR, dtproj_b + l * EE,
            EE, RR, 96, RR, EE);
        scan_kernel<<<dim3(BB * EE), blk, 0, stream>>>(
            yb, dtb, xm, xdb, xzb, A_log + l * EE * NN, Dp + l * EE);
        // h += y @ outproj^T (N=1024, K=2048) : NT=4 -> grid 16x16
        mgemm_kernel<3, 4, 0><<<dim3(DM_ / 64, BL / 128), blk, 0, stream>>>(
            h, yb, outprojb + (size_t)l * DM_ * EE, nullptr,
            DM_, EE, EE, EE, DM_);
    }

    layernorm_kernel<<<dim3(BL), blk, 0, stream>>>(hnb, h, fnorm_w, fnorm_b);
    // out = hn @ op_w^T + op_b (N=512, K=1024) : NT=4 -> grid 8x16
    mgemm_kernel<1, 4, 0><<<dim3(DIN_ / 64, BL / 128), blk, 0, stream>>>(
        out, hnb, opwb, op_b, DIN_, DM_, DM_, DM_, DIN_);
}

// Round 4
// 1284.671 us; speedup vs baseline: 5.5207x; 1.2882x over previous
//
#include <hip/hip_runtime.h>
#include <math.h>

#define BB 2
#define LL 1024
#define DIN_ 512
#define DM_ 1024
#define NL_ 4
#define EE 2048
#define NN 16
#define RR 64
#define KK 4

#define NC 32   // scan chunks
#define CT 32   // timesteps per chunk (NC*CT == LL)

typedef unsigned short ushort_t;
typedef unsigned int uint_t;

using frag_ab = __attribute__((ext_vector_type(8))) short;
using frag_cd = __attribute__((ext_vector_type(4))) float;

__device__ __forceinline__ float softplus_f(float x) {
    return fmaxf(x, 0.f) + log1pf(expf(-fabsf(x)));
}
__device__ __forceinline__ float silu_f(float x) {
    return x / (1.f + expf(-x));
}
__device__ __forceinline__ float bf2f(ushort_t x) {
    return __uint_as_float((uint_t)x << 16);
}
__device__ __forceinline__ ushort_t f2bf(float x) {
    uint_t u = __float_as_uint(x);
    uint_t r = (u + 0x7fffu + ((u >> 16) & 1u)) >> 16;   // RNE
    return (ushort_t)r;
}
__device__ __forceinline__ void gload_lds16(const void* g, void* l) {
    __builtin_amdgcn_global_load_lds(
        (const __attribute__((address_space(1))) void*)g,
        (__attribute__((address_space(3))) void*)l, 16, 0, 0);
}

// ---------------------------------------------------------------------------
// fp32 -> bf16 convert (n multiple of 4)
// ---------------------------------------------------------------------------
__global__ __launch_bounds__(256) void cvt_bf16_kernel(
    ushort_t* __restrict__ o, const float* __restrict__ in, int n4)
{
    int i = blockIdx.x * 256 + threadIdx.x;
    if (i >= n4) return;
    float4 v = ((const float4*)in)[i];
    ushort4 u;
    u.x = f2bf(v.x); u.y = f2bf(v.y); u.z = f2bf(v.z); u.w = f2bf(v.w);
    ((ushort4*)o)[i] = u;
}

__global__ __launch_bounds__(256) void zero_kernel(float* __restrict__ p, int n4)
{
    int i = blockIdx.x * 256 + threadIdx.x;
    if (i < n4) ((float4*)p)[i] = make_float4(0.f, 0.f, 0.f, 0.f);
}

// ---------------------------------------------------------------------------
// bf16 MFMA GEMM (unchanged from round 3; verified).
// ---------------------------------------------------------------------------
template <int EPI, int NT, int OUTBF>
__global__ __launch_bounds__(256) void mgemm_kernel(
    void* __restrict__ Cp, const ushort_t* __restrict__ A,
    const ushort_t* __restrict__ W, const float* __restrict__ bias,
    int N, int K, int lda, int ldw, int ldc)
{
    __shared__ __attribute__((aligned(16))) ushort_t As[8 * 512];
    __shared__ __attribute__((aligned(16))) ushort_t Bs[NT * 512];

    const int tid = threadIdx.x;
    const int w = tid >> 6;
    const int lane = tid & 63;
    const int r = lane & 15;
    const int q = lane >> 4;
    const int m0 = blockIdx.y * 128;
    const int n0 = blockIdx.x * (NT * 16);
    const int wm = w >> 1;
    const int wn = w & 1;
    const int NWT = NT / 2;

    frag_cd acc[4][NWT];
#pragma unroll
    for (int i = 0; i < 4; i++)
#pragma unroll
        for (int j = 0; j < NWT; j++)
#pragma unroll
            for (int t = 0; t < 4; t++) acc[i][j][t] = 0.f;

    size_t koff = (EPI == 4) ? (size_t)blockIdx.z * K : 0;
    const ushort_t* Ab = A + (size_t)m0 * lda + koff;
    const ushort_t* Wb = W + (size_t)n0 * ldw + koff;

    const int NFRAG = 8 + NT;
    for (int k0 = 0; k0 < K; k0 += 32) {
        for (int F = w; F < NFRAG; F += 4) {
            if (F < 8) {
                const ushort_t* g = Ab + (size_t)(F * 16 + r) * lda + k0 + q * 8;
                gload_lds16(g, As + F * 512);
            } else {
                int nt = F - 8;
                if (n0 + nt * 16 + r < N) {
                    const ushort_t* g = Wb + (size_t)(nt * 16 + r) * ldw + k0 + q * 8;
                    gload_lds16(g, Bs + nt * 512);
                }
            }
        }
        __syncthreads();
        frag_ab af[4], bf[NWT];
#pragma unroll
        for (int i = 0; i < 4; i++)
            af[i] = *(const frag_ab*)(As + (wm * 4 + i) * 512 + lane * 8);
#pragma unroll
        for (int j = 0; j < NWT; j++)
            bf[j] = *(const frag_ab*)(Bs + (wn * NWT + j) * 512 + lane * 8);
#pragma unroll
        for (int i = 0; i < 4; i++)
#pragma unroll
            for (int j = 0; j < NWT; j++)
                acc[i][j] = __builtin_amdgcn_mfma_f32_16x16x32_bf16(
                    af[i], bf[j], acc[i][j], 0, 0, 0);
        __syncthreads();
    }

    float* Cf = (float*)Cp;
    ushort_t* Cb = (ushort_t*)Cp;
#pragma unroll
    for (int i = 0; i < 4; i++) {
        int mrow = m0 + (wm * 4 + i) * 16 + q * 4;
#pragma unroll
        for (int j = 0; j < NWT; j++) {
            int col = n0 + (wn * NWT + j) * 16 + r;
            if (col >= N) continue;
            float bv = (EPI == 1 || EPI == 2) ? bias[col] : 0.f;
#pragma unroll
            for (int t = 0; t < 4; t++) {
                float v = acc[i][j][t];
                size_t idx = (size_t)(mrow + t) * ldc + col;
                if (EPI == 4) { atomicAdd(Cf + idx, v); continue; }
                if (EPI == 1) v += bv;
                if (EPI == 2) v = softplus_f(v + bv);
                if (EPI == 3) v += Cf[idx];
                if (OUTBF) Cb[idx] = f2bf(v);
                else       Cf[idx] = v;
            }
        }
    }
}

// ---------------------------------------------------------------------------
// Row LayerNorm over D=1024 (fp32 in), bf16 out.
// ---------------------------------------------------------------------------
__global__ __launch_bounds__(256) void layernorm_kernel(
    ushort_t* __restrict__ out, const float* __restrict__ in,
    const float* __restrict__ w, const float* __restrict__ b)
{
    const int row = blockIdx.x;
    const int tid = threadIdx.x;
    float4 v = ((const float4*)(in + (size_t)row * DM_))[tid];
    float s = v.x + v.y + v.z + v.w;
    float sq = v.x * v.x + v.y * v.y + v.z * v.z + v.w * v.w;
#pragma unroll
    for (int off = 32; off; off >>= 1) {
        s += __shfl_down(s, off);
        sq += __shfl_down(sq, off);
    }
    __shared__ float ls[4], lq[4];
    int wid = tid >> 6;
    if ((tid & 63) == 0) { ls[wid] = s; lq[wid] = sq; }
    __syncthreads();
    float S = ls[0] + ls[1] + ls[2] + ls[3];
    float Q = lq[0] + lq[1] + lq[2] + lq[3];
    float mean = S * (1.f / DM_);
    float var = Q * (1.f / DM_) - mean * mean;
    float inv = rsqrtf(var + 1e-5f);
    float4 wv = ((const float4*)w)[tid];
    float4 bv = ((const float4*)b)[tid];
    ushort4 o;
    o.x = f2bf((v.x - mean) * inv * wv.x + bv.x);
    o.y = f2bf((v.y - mean) * inv * wv.y + bv.y);
    o.z = f2bf((v.z - mean) * inv * wv.z + bv.z);
    o.w = f2bf((v.w - mean) * inv * wv.w + bv.w);
    ((ushort4*)(out + (size_t)row * DM_))[tid] = o;
}

// ---------------------------------------------------------------------------
// Causal depthwise conv (K=4) on bf16 xz (x-half), + bias, + SiLU -> bf16 xm
// ---------------------------------------------------------------------------
__global__ __launch_bounds__(256) void conv_silu_kernel(
    ushort_t* __restrict__ xm, const ushort_t* __restrict__ xz,
    const float* __restrict__ cw, const float* __restrict__ cb)
{
    const int e = blockIdx.x * 256 + threadIdx.x;
    const int l = blockIdx.y;
    const int b = blockIdx.z;
    const ushort_t* X = xz + (size_t)b * LL * 2 * EE + e;
    float4 w4 = ((const float4*)cw)[e];
    float wk[4] = {w4.x, w4.y, w4.z, w4.w};
    float acc = cb[e];
#pragma unroll
    for (int k = 0; k < 4; k++) {
        int t = l + k - 3;
        if (t >= 0) acc = fmaf(wk[k], bf2f(X[(size_t)t * 2 * EE]), acc);
    }
    xm[((size_t)b * LL + l) * EE + e] = f2bf(silu_f(acc));
}

// ---------------------------------------------------------------------------
// Thread-per-channel chunked scan, 3 kernels.
// Layout: thread <-> (b, e); lanes cover consecutive e (coalesced dt/u/zg/y).
// Each thread carries 16 states in registers. B/C staged per-chunk in LDS
// (CT x 16 floats each), read broadcast.
//
// phase1: grid (E/256, NC, B). For chunk c: P_n = prod dA, S_n = local scan.
//   Writes Pg/Sg[((b*NC+c)*E+e)*16+n].
// combine: h_start(c+1) = S(c) + P(c)*h_start(c), in-place: Pg slot c gets
//   h_start(c+1); phase2 chunk c reads Pg slot c-1 (chunk 0: h=0).
// phase2: replay chunk with h init, y = sum_n h*C; out = (y+u*D)*silu(zg).
// ---------------------------------------------------------------------------
__global__ __launch_bounds__(256) void scan_phase1_kernel(
    float* __restrict__ Pg, float* __restrict__ Sg,
    const float* __restrict__ dt, const ushort_t* __restrict__ u,
    const float* __restrict__ xdb, const float* __restrict__ A_log)
{
    const int tid = threadIdx.x;
    const int e = blockIdx.x * 256 + tid;
    const int c = blockIdx.y;
    const int b = blockIdx.z;
    const int t0 = c * CT;

    __shared__ float Bs[CT][16], Cs[CT][16];
    {
        int tt = tid >> 3;
        int jj = tid & 7;
        float4 v = *(const float4*)(xdb + ((size_t)(b * LL + t0 + tt) * 96 + 64 + jj * 4));
        if (jj < 4) *(float4*)&Bs[tt][jj * 4] = v;
        else        *(float4*)&Cs[tt][(jj - 4) * 4] = v;
    }
    __syncthreads();

    float Ae[16];
#pragma unroll
    for (int k = 0; k < 4; k++) {
        float4 a = *(const float4*)(A_log + (size_t)e * NN + k * 4);
        Ae[k * 4 + 0] = -expf(a.x);
        Ae[k * 4 + 1] = -expf(a.y);
        Ae[k * 4 + 2] = -expf(a.z);
        Ae[k * 4 + 3] = -expf(a.w);
    }

    float P[16], S[16];
#pragma unroll
    for (int n = 0; n < 16; n++) { P[n] = 1.f; S[n] = 0.f; }

    const float* dt_p = dt + (size_t)(b * LL + t0) * EE + e;
    const ushort_t* u_p = u + (size_t)(b * LL + t0) * EE + e;

    for (int i = 0; i < CT; i++) {
        float dtv = dt_p[(size_t)i * EE];
        float uv = bf2f(u_p[(size_t)i * EE]);
        float dtu = dtv * uv;
        float Bv[16];
#pragma unroll
        for (int k = 0; k < 4; k++)
            *(float4*)&Bv[k * 4] = *(const float4*)&Bs[i][k * 4];
#pragma unroll
        for (int n = 0; n < 16; n++) {
            float da = expf(dtv * Ae[n]);
            S[n] = fmaf(da, S[n], dtu * Bv[n]);
            P[n] *= da;
        }
    }

    size_t o = ((size_t)(b * NC + c) * EE + e) * 16;
#pragma unroll
    for (int k = 0; k < 4; k++) {
        *(float4*)(Pg + o + k * 4) = *(float4*)&P[k * 4];
        *(float4*)(Sg + o + k * 4) = *(float4*)&S[k * 4];
    }
}

__global__ __launch_bounds__(256) void scan_combine_kernel(
    float* __restrict__ Pg, const float* __restrict__ Sg)
{
    const int f = blockIdx.x * 256 + threadIdx.x;   // (e,n) flat, n fastest
    const int b = blockIdx.y;
    float h = 0.f;
    for (int c = 0; c < NC; c++) {
        size_t o = (size_t)(b * NC + c) * EE * 16 + f;
        float p = Pg[o];
        float s = Sg[o];
        h = fmaf(p, h, s);      // h_start(c+1)
        Pg[o] = h;
    }
}

__global__ __launch_bounds__(256) void scan_phase2_kernel(
    ushort_t* __restrict__ y, const float* __restrict__ Pg,
    const float* __restrict__ dt, const ushort_t* __restrict__ u,
    const float* __restrict__ xdb, const ushort_t* __restrict__ xz,
    const float* __restrict__ A_log, const float* __restrict__ Dp)
{
    const int tid = threadIdx.x;
    const int e = blockIdx.x * 256 + tid;
    const int c = blockIdx.y;
    const int b = blockIdx.z;
    const int t0 = c * CT;

    __shared__ float Bs[CT][16], Cs[CT][16];
    {
        int tt = tid >> 3;
        int jj = tid & 7;
        float4 v = *(const float4*)(xdb + ((size_t)(b * LL + t0 + tt) * 96 + 64 + jj * 4));
        if (jj < 4) *(float4*)&Bs[tt][jj * 4] = v;
        else        *(float4*)&Cs[tt][(jj - 4) * 4] = v;
    }
    __syncthreads();

    float Ae[16];
#pragma unroll
    for (int k = 0; k < 4; k++) {
        float4 a = *(const float4*)(A_log + (size_t)e * NN + k * 4);
        Ae[k * 4 + 0] = -expf(a.x);
        Ae[k * 4 + 1] = -expf(a.y);
        Ae[k * 4 + 2] = -expf(a.z);
        Ae[k * 4 + 3] = -expf(a.w);
    }

    float h[16];
    if (c == 0) {
#pragma unroll
        for (int n = 0; n < 16; n++) h[n] = 0.f;
    } else {
        size_t o = ((size_t)(b * NC + (c - 1)) * EE + e) * 16;
#pragma unroll
        for (int k = 0; k < 4; k++)
            *(float4*)&h[k * 4] = *(const float4*)(Pg + o + k * 4);
    }

    const float Dv = Dp[e];
    const float* dt_p = dt + (size_t)(b * LL + t0) * EE + e;
    const ushort_t* u_p = u + (size_t)(b * LL + t0) * EE + e;
    const ushort_t* zg_p = xz + (size_t)(b * LL + t0) * 2 * EE + EE + e;
    ushort_t* y_p = y + (size_t)(b * LL + t0) * EE + e;

    for (int i = 0; i < CT; i++) {
        float dtv = dt_p[(size_t)i * EE];
        float uv = bf2f(u_p[(size_t)i * EE]);
        float zv = bf2f(zg_p[(size_t)i * 2 * EE]);
        float dtu = dtv * uv;
        float Bv[16], Cv[16];
#pragma unroll
        for (int k = 0; k < 4; k++) {
            *(float4*)&Bv[k * 4] = *(const float4*)&Bs[i][k * 4];
            *(float4*)&Cv[k * 4] = *(const float4*)&Cs[i][k * 4];
        }
        float yv = 0.f;
#pragma unroll
        for (int n = 0; n < 16; n++) {
            float da = expf(dtv * Ae[n]);
            h[n] = fmaf(da, h[n], dtu * Bv[n]);
            yv = fmaf(h[n], Cv[n], yv);
        }
        y_p[(size_t)i * EE] = f2bf((yv + uv * Dv) * silu_f(zv));
    }
}

// ---------------------------------------------------------------------------
extern "C" void kernel_launch(void* const* d_in, const int* in_sizes, int n_in,
                              void* d_out, int out_size, void* d_ws, size_t ws_size,
                              hipStream_t stream)
{
    const float* x = (const float*)d_in[0];
    const float* ip_w = (const float*)d_in[2];
    const float* ip_b = (const float*)d_in[3];
    const float* ln_w = (const float*)d_in[4];
    const float* ln_b = (const float*)d_in[5];
    const float* inproj_w = (const float*)d_in[6];
    const float* conv_w = (const float*)d_in[7];
    const float* conv_b = (const float*)d_in[8];
    const float* xproj_w = (const float*)d_in[9];
    const float* dtproj_w = (const float*)d_in[10];
    const float* dtproj_b = (const float*)d_in[11];
    const float* A_log = (const float*)d_in[12];
    const float* Dp = (const float*)d_in[13];
    const float* outproj_w = (const float*)d_in[14];
    const float* fnorm_w = (const float*)d_in[15];
    const float* fnorm_b = (const float*)d_in[16];
    const float* op_w = (const float*)d_in[17];
    const float* op_b = (const float*)d_in[18];
    float* out = (float*)d_out;

    const size_t BL = (size_t)BB * LL;   // 2048

    // ---- workspace layout: fp32 region then bf16 region
    float* fp = (float*)d_ws;
    float* h = fp;           fp += BL * DM_;
    float* xdb = fp;         fp += BL * 96;
    float* dtb = fp;         fp += BL * EE;
    float* Pg = fp;          fp += (size_t)BB * NC * EE * 16;   // 2.1M floats
    float* Sg = fp;          fp += (size_t)BB * NC * EE * 16;
    ushort_t* us = (ushort_t*)fp;
    ushort_t* xb = us;       us += BL * DIN_;
    ushort_t* hnb = us;      us += BL * DM_;
    ushort_t* xzb = us;      us += BL * 2 * EE;
    ushort_t* xm = us;       us += BL * EE;
    ushort_t* xdbb = us;     us += BL * 96;
    ushort_t* yb = us;       us += BL * EE;
    ushort_t* ipwb = us;     us += (size_t)DM_ * DIN_;
    ushort_t* inprojb = us;  us += (size_t)NL_ * 2 * EE * DM_;
    ushort_t* xprojb = us;   us += (size_t)NL_ * 96 * EE;
    ushort_t* dtprojb = us;  us += (size_t)NL_ * EE * RR;
    ushort_t* outprojb = us; us += (size_t)NL_ * DM_ * EE;
    ushort_t* opwb = us;     us += (size_t)DIN_ * DM_;

    dim3 blk(256);
    auto cvt = [&](ushort_t* dst, const float* src, size_t n) {
        int n4 = (int)(n / 4);
        cvt_bf16_kernel<<<dim3((n4 + 255) / 256), blk, 0, stream>>>(dst, src, n4);
    };

    cvt(xb, x, BL * DIN_);
    cvt(ipwb, ip_w, (size_t)DM_ * DIN_);
    cvt(inprojb, inproj_w, (size_t)NL_ * 2 * EE * DM_);
    cvt(xprojb, xproj_w, (size_t)NL_ * 96 * EE);
    cvt(dtprojb, dtproj_w, (size_t)NL_ * EE * RR);
    cvt(outprojb, outproj_w, (size_t)NL_ * DM_ * EE);
    cvt(opwb, op_w, (size_t)DIN_ * DM_);

    // ---- h = x @ ip_w^T + ip_b
    mgemm_kernel<1, 4, 0><<<dim3(DM_ / 64, BL / 128), blk, 0, stream>>>(
        h, xb, ipwb, ip_b, DM_, DIN_, DIN_, DIN_, DM_);

    for (int l = 0; l < NL_; l++) {
        layernorm_kernel<<<dim3(BL), blk, 0, stream>>>(hnb, h, ln_w + l * DM_, ln_b + l * DM_);
        mgemm_kernel<0, 8, 1><<<dim3(2 * EE / 128, BL / 128), blk, 0, stream>>>(
            xzb, hnb, inprojb + (size_t)l * 2 * EE * DM_, nullptr,
            2 * EE, DM_, DM_, DM_, 2 * EE);
        conv_silu_kernel<<<dim3(EE / 256, LL, BB), blk, 0, stream>>>(
            xm, xzb, conv_w + l * EE * KK, conv_b + l * EE);
        zero_kernel<<<dim3((int)(BL * 96 / 4 + 255) / 256), blk, 0, stream>>>(xdb, (int)(BL * 96 / 4));
        mgemm_kernel<4, 8, 0><<<dim3(1, BL / 128, 16), blk, 0, stream>>>(
            xdb, xm, xprojb + (size_t)l * 96 * EE, nullptr,
            96, EE / 16, EE, EE, 96);
        cvt(xdbb, xdb, BL * 96);
        mgemm_kernel<2, 8, 0><<<dim3(EE / 128, BL / 128), blk, 0, stream>>>(
            dtb, xdbb, dtprojb + (size_t)l * EE * RR, dtproj_b + l * EE,
            EE, RR, 96, RR, EE);

        // ---- chunked scan: phase1 -> combine -> phase2
        scan_phase1_kernel<<<dim3(EE / 256, NC, BB), blk, 0, stream>>>(
            Pg, Sg, dtb, xm, xdb, A_log + (size_t)l * EE * NN);
        scan_combine_kernel<<<dim3(EE * 16 / 256, BB), blk, 0, stream>>>(Pg, Sg);
        scan_phase2_kernel<<<dim3(EE / 256, NC, BB), blk, 0, stream>>>(
            yb, Pg, dtb, xm, xdb, xzb, A_log + (size_t)l * EE * NN, Dp + l * EE);

        mgemm_kernel<3, 4, 0><<<dim3(DM_ / 64, BL / 128), blk, 0, stream>>>(
            h, yb, outprojb + (size_t)l * DM_ * EE, nullptr,
            DM_, EE, EE, EE, DM_);
    }

    layernorm_kernel<<<dim3(BL), blk, 0, stream>>>(hnb, h, fnorm_w, fnorm_b);
    mgemm_kernel<1, 4, 0><<<dim3(DIN_ / 64, BL / 128), blk, 0, stream>>>(
        out, hnb, opwb, op_b, DIN_, DM_, DM_, DM_, DIN_);
}

// Round 5
// 1189.595 us; speedup vs baseline: 5.9619x; 1.0799x over previous
//
#include <hip/hip_runtime.h>
#include <math.h>

#define BB 2
#define LL 1024
#define DIN_ 512
#define DM_ 1024
#define NL_ 4
#define EE 2048
#define NN 16
#define RR 64
#define KK 4

#define NC 32   // scan chunks
#define CT 32   // timesteps per chunk (NC*CT == LL)

typedef unsigned short ushort_t;
typedef unsigned int uint_t;

using frag_ab = __attribute__((ext_vector_type(8))) short;
using frag_cd = __attribute__((ext_vector_type(4))) float;

__device__ __forceinline__ float softplus_f(float x) {
    return fmaxf(x, 0.f) + log1pf(expf(-fabsf(x)));
}
__device__ __forceinline__ float silu_f(float x) {
    return x / (1.f + expf(-x));
}
__device__ __forceinline__ float bf2f(ushort_t x) {
    return __uint_as_float((uint_t)x << 16);
}
__device__ __forceinline__ ushort_t f2bf(float x) {
    uint_t u = __float_as_uint(x);
    uint_t r = (u + 0x7fffu + ((u >> 16) & 1u)) >> 16;   // RNE
    return (ushort_t)r;
}
__device__ __forceinline__ void gload_lds16(const void* g, void* l) {
    __builtin_amdgcn_global_load_lds(
        (const __attribute__((address_space(1))) void*)g,
        (__attribute__((address_space(3))) void*)l, 16, 0, 0);
}

// ---------------------------------------------------------------------------
// fp32 -> bf16 convert (n multiple of 4)
// ---------------------------------------------------------------------------
__global__ __launch_bounds__(256) void cvt_bf16_kernel(
    ushort_t* __restrict__ o, const float* __restrict__ in, int n4)
{
    int i = blockIdx.x * 256 + threadIdx.x;
    if (i >= n4) return;
    float4 v = ((const float4*)in)[i];
    ushort4 u;
    u.x = f2bf(v.x); u.y = f2bf(v.y); u.z = f2bf(v.z); u.w = f2bf(v.w);
    ((ushort4*)o)[i] = u;
}

__global__ __launch_bounds__(256) void zero_kernel(float* __restrict__ p, int n4)
{
    int i = blockIdx.x * 256 + threadIdx.x;
    if (i < n4) ((float4*)p)[i] = make_float4(0.f, 0.f, 0.f, 0.f);
}

// dst[m, n] = bias[n] for all m  (n4 = N/4, total = M*N/4 float4s)
__global__ __launch_bounds__(256) void rowbias_kernel(
    float* __restrict__ dst, const float* __restrict__ bias, int n4, int total4)
{
    int i = blockIdx.x * 256 + threadIdx.x;
    if (i >= total4) return;
    int c = i % n4;
    ((float4*)dst)[i] = ((const float4*)bias)[c];
}

// ---------------------------------------------------------------------------
// bf16 MFMA GEMM with double-buffered LDS staging.
// Tile: M=128 x N=NT*16, BK=32. 256 thr = 2x2 waves, wave = 4m x NT/2 n MFMA
// tiles (16x16x32). Fragment-ordered LDS (frag = contiguous 1024B, lane order)
// -> global_load_lds legal + conflict-free ds_read_b128.
// Double buffer: one barrier/iter; prefetch k+1 issued right after barrier,
// drained by next iter's barrier (full compute phase in flight).
// EPI: 0 none, 1 +bias, 2 softplus(+bias), 3 C+=acc,
//      4 atomicAdd fp32 (split-K via blockIdx.z; K = chunk size)
// ---------------------------------------------------------------------------
template <int EPI, int NT, int OUTBF>
__global__ __launch_bounds__(256) void mgemm_kernel(
    void* __restrict__ Cp, const ushort_t* __restrict__ A,
    const ushort_t* __restrict__ W, const float* __restrict__ bias,
    int N, int K, int lda, int ldw, int ldc)
{
    __shared__ __attribute__((aligned(16))) ushort_t As[2][8 * 512];
    __shared__ __attribute__((aligned(16))) ushort_t Bs[2][NT * 512];

    const int tid = threadIdx.x;
    const int w = tid >> 6;
    const int lane = tid & 63;
    const int r = lane & 15;
    const int q = lane >> 4;
    const int m0 = blockIdx.y * 128;
    const int n0 = blockIdx.x * (NT * 16);
    const int wm = w >> 1;
    const int wn = w & 1;
    const int NWT = NT / 2;

    frag_cd acc[4][NWT];
#pragma unroll
    for (int i = 0; i < 4; i++)
#pragma unroll
        for (int j = 0; j < NWT; j++)
#pragma unroll
            for (int t = 0; t < 4; t++) acc[i][j][t] = 0.f;

    size_t koff = (EPI == 4) ? (size_t)blockIdx.z * K : 0;
    const ushort_t* Ab = A + (size_t)m0 * lda + koff;
    const ushort_t* Wb = W + (size_t)n0 * ldw + koff;

    const int NFRAG = 8 + NT;
    auto stage = [&](int k0, int buf) {
        for (int F = w; F < NFRAG; F += 4) {
            if (F < 8) {
                gload_lds16(Ab + (size_t)(F * 16 + r) * lda + k0 + q * 8,
                            &As[buf][F * 512]);
            } else {
                int nt = F - 8;
                if (n0 + nt * 16 + r < N)
                    gload_lds16(Wb + (size_t)(nt * 16 + r) * ldw + k0 + q * 8,
                                &Bs[buf][nt * 512]);
            }
        }
    };

    stage(0, 0);
    int buf = 0;
    for (int k0 = 0; k0 < K; k0 += 32) {
        __syncthreads();                  // drains this buf's staging (vmcnt 0)
        if (k0 + 32 < K) stage(k0 + 32, buf ^ 1);   // async prefetch
        frag_ab af[4], bf[NWT];
#pragma unroll
        for (int i = 0; i < 4; i++)
            af[i] = *(const frag_ab*)(&As[buf][(wm * 4 + i) * 512] + lane * 8);
#pragma unroll
        for (int j = 0; j < NWT; j++)
            bf[j] = *(const frag_ab*)(&Bs[buf][(wn * NWT + j) * 512] + lane * 8);
#pragma unroll
        for (int i = 0; i < 4; i++)
#pragma unroll
            for (int j = 0; j < NWT; j++)
                acc[i][j] = __builtin_amdgcn_mfma_f32_16x16x32_bf16(
                    af[i], bf[j], acc[i][j], 0, 0, 0);
        buf ^= 1;
        // next barrier also protects buf re-staging: all waves' ds_reads of
        // the (new) buf completed before they pass it (lgkmcnt in barrier).
    }

    float* Cf = (float*)Cp;
    ushort_t* Cb = (ushort_t*)Cp;
#pragma unroll
    for (int i = 0; i < 4; i++) {
        int mrow = m0 + (wm * 4 + i) * 16 + q * 4;
#pragma unroll
        for (int j = 0; j < NWT; j++) {
            int col = n0 + (wn * NWT + j) * 16 + r;
            if (col >= N) continue;
            float bv = (EPI == 1 || EPI == 2) ? bias[col] : 0.f;
#pragma unroll
            for (int t = 0; t < 4; t++) {
                float v = acc[i][j][t];
                size_t idx = (size_t)(mrow + t) * ldc + col;
                if (EPI == 4) { atomicAdd(Cf + idx, v); continue; }
                if (EPI == 1) v += bv;
                if (EPI == 2) v = softplus_f(v + bv);
                if (EPI == 3) v += Cf[idx];
                if (OUTBF) Cb[idx] = f2bf(v);
                else       Cf[idx] = v;
            }
        }
    }
}

// ---------------------------------------------------------------------------
// Row LayerNorm over D=1024 (fp32 in), bf16 out.
// ---------------------------------------------------------------------------
__global__ __launch_bounds__(256) void layernorm_kernel(
    ushort_t* __restrict__ out, const float* __restrict__ in,
    const float* __restrict__ w, const float* __restrict__ b)
{
    const int row = blockIdx.x;
    const int tid = threadIdx.x;
    float4 v = ((const float4*)(in + (size_t)row * DM_))[tid];
    float s = v.x + v.y + v.z + v.w;
    float sq = v.x * v.x + v.y * v.y + v.z * v.z + v.w * v.w;
#pragma unroll
    for (int off = 32; off; off >>= 1) {
        s += __shfl_down(s, off);
        sq += __shfl_down(sq, off);
    }
    __shared__ float ls[4], lq[4];
    int wid = tid >> 6;
    if ((tid & 63) == 0) { ls[wid] = s; lq[wid] = sq; }
    __syncthreads();
    float S = ls[0] + ls[1] + ls[2] + ls[3];
    float Q = lq[0] + lq[1] + lq[2] + lq[3];
    float mean = S * (1.f / DM_);
    float var = Q * (1.f / DM_) - mean * mean;
    float inv = rsqrtf(var + 1e-5f);
    float4 wv = ((const float4*)w)[tid];
    float4 bv = ((const float4*)b)[tid];
    ushort4 o;
    o.x = f2bf((v.x - mean) * inv * wv.x + bv.x);
    o.y = f2bf((v.y - mean) * inv * wv.y + bv.y);
    o.z = f2bf((v.z - mean) * inv * wv.z + bv.z);
    o.w = f2bf((v.w - mean) * inv * wv.w + bv.w);
    ((ushort4*)(out + (size_t)row * DM_))[tid] = o;
}

// ---------------------------------------------------------------------------
// Causal depthwise conv (K=4) on bf16 xz (x-half), + bias, + SiLU -> bf16 xm
// ---------------------------------------------------------------------------
__global__ __launch_bounds__(256) void conv_silu_kernel(
    ushort_t* __restrict__ xm, const ushort_t* __restrict__ xz,
    const float* __restrict__ cw, const float* __restrict__ cb)
{
    const int e = blockIdx.x * 256 + threadIdx.x;
    const int l = blockIdx.y;
    const int b = blockIdx.z;
    const ushort_t* X = xz + (size_t)b * LL * 2 * EE + e;
    float4 w4 = ((const float4*)cw)[e];
    float wk[4] = {w4.x, w4.y, w4.z, w4.w};
    float acc = cb[e];
#pragma unroll
    for (int k = 0; k < 4; k++) {
        int t = l + k - 3;
        if (t >= 0) acc = fmaf(wk[k], bf2f(X[(size_t)t * 2 * EE]), acc);
    }
    xm[((size_t)b * LL + l) * EE + e] = f2bf(silu_f(acc));
}

// ---------------------------------------------------------------------------
// Thread-per-channel chunked scan (verified round 4).
// ---------------------------------------------------------------------------
__global__ __launch_bounds__(256) void scan_phase1_kernel(
    float* __restrict__ Pg, float* __restrict__ Sg,
    const float* __restrict__ dt, const ushort_t* __restrict__ u,
    const float* __restrict__ xdb, const float* __restrict__ A_log)
{
    const int tid = threadIdx.x;
    const int e = blockIdx.x * 256 + tid;
    const int c = blockIdx.y;
    const int b = blockIdx.z;
    const int t0 = c * CT;

    __shared__ float Bs[CT][16], Cs[CT][16];
    {
        int tt = tid >> 3;
        int jj = tid & 7;
        float4 v = *(const float4*)(xdb + ((size_t)(b * LL + t0 + tt) * 96 + 64 + jj * 4));
        if (jj < 4) *(float4*)&Bs[tt][jj * 4] = v;
        else        *(float4*)&Cs[tt][(jj - 4) * 4] = v;
    }
    __syncthreads();

    float Ae[16];
#pragma unroll
    for (int k = 0; k < 4; k++) {
        float4 a = *(const float4*)(A_log + (size_t)e * NN + k * 4);
        Ae[k * 4 + 0] = -expf(a.x);
        Ae[k * 4 + 1] = -expf(a.y);
        Ae[k * 4 + 2] = -expf(a.z);
        Ae[k * 4 + 3] = -expf(a.w);
    }

    float P[16], S[16];
#pragma unroll
    for (int n = 0; n < 16; n++) { P[n] = 1.f; S[n] = 0.f; }

    const float* dt_p = dt + (size_t)(b * LL + t0) * EE + e;
    const ushort_t* u_p = u + (size_t)(b * LL + t0) * EE + e;

    for (int i = 0; i < CT; i++) {
        float dtv = dt_p[(size_t)i * EE];
        float uv = bf2f(u_p[(size_t)i * EE]);
        float dtu = dtv * uv;
        float Bv[16];
#pragma unroll
        for (int k = 0; k < 4; k++)
            *(float4*)&Bv[k * 4] = *(const float4*)&Bs[i][k * 4];
#pragma unroll
        for (int n = 0; n < 16; n++) {
            float da = expf(dtv * Ae[n]);
            S[n] = fmaf(da, S[n], dtu * Bv[n]);
            P[n] *= da;
        }
    }

    size_t o = ((size_t)(b * NC + c) * EE + e) * 16;
#pragma unroll
    for (int k = 0; k < 4; k++) {
        *(float4*)(Pg + o + k * 4) = *(float4*)&P[k * 4];
        *(float4*)(Sg + o + k * 4) = *(float4*)&S[k * 4];
    }
}

__global__ __launch_bounds__(256) void scan_combine_kernel(
    float* __restrict__ Pg, const float* __restrict__ Sg)
{
    const int f = blockIdx.x * 256 + threadIdx.x;
    const int b = blockIdx.y;
    float h = 0.f;
    for (int c = 0; c < NC; c++) {
        size_t o = (size_t)(b * NC + c) * EE * 16 + f;
        float p = Pg[o];
        float s = Sg[o];
        h = fmaf(p, h, s);
        Pg[o] = h;
    }
}

__global__ __launch_bounds__(256) void scan_phase2_kernel(
    ushort_t* __restrict__ y, const float* __restrict__ Pg,
    const float* __restrict__ dt, const ushort_t* __restrict__ u,
    const float* __restrict__ xdb, const ushort_t* __restrict__ xz,
    const float* __restrict__ A_log, const float* __restrict__ Dp)
{
    const int tid = threadIdx.x;
    const int e = blockIdx.x * 256 + tid;
    const int c = blockIdx.y;
    const int b = blockIdx.z;
    const int t0 = c * CT;

    __shared__ float Bs[CT][16], Cs[CT][16];
    {
        int tt = tid >> 3;
        int jj = tid & 7;
        float4 v = *(const float4*)(xdb + ((size_t)(b * LL + t0 + tt) * 96 + 64 + jj * 4));
        if (jj < 4) *(float4*)&Bs[tt][jj * 4] = v;
        else        *(float4*)&Cs[tt][(jj - 4) * 4] = v;
    }
    __syncthreads();

    float Ae[16];
#pragma unroll
    for (int k = 0; k < 4; k++) {
        float4 a = *(const float4*)(A_log + (size_t)e * NN + k * 4);
        Ae[k * 4 + 0] = -expf(a.x);
        Ae[k * 4 + 1] = -expf(a.y);
        Ae[k * 4 + 2] = -expf(a.z);
        Ae[k * 4 + 3] = -expf(a.w);
    }

    float h[16];
    if (c == 0) {
#pragma unroll
        for (int n = 0; n < 16; n++) h[n] = 0.f;
    } else {
        size_t o = ((size_t)(b * NC + (c - 1)) * EE + e) * 16;
#pragma unroll
        for (int k = 0; k < 4; k++)
            *(float4*)&h[k * 4] = *(const float4*)(Pg + o + k * 4);
    }

    const float Dv = Dp[e];
    const float* dt_p = dt + (size_t)(b * LL + t0) * EE + e;
    const ushort_t* u_p = u + (size_t)(b * LL + t0) * EE + e;
    const ushort_t* zg_p = xz + (size_t)(b * LL + t0) * 2 * EE + EE + e;
    ushort_t* y_p = y + (size_t)(b * LL + t0) * EE + e;

    for (int i = 0; i < CT; i++) {
        float dtv = dt_p[(size_t)i * EE];
        float uv = bf2f(u_p[(size_t)i * EE]);
        float zv = bf2f(zg_p[(size_t)i * 2 * EE]);
        float dtu = dtv * uv;
        float Bv[16], Cv[16];
#pragma unroll
        for (int k = 0; k < 4; k++) {
            *(float4*)&Bv[k * 4] = *(const float4*)&Bs[i][k * 4];
            *(float4*)&Cv[k * 4] = *(const float4*)&Cs[i][k * 4];
        }
        float yv = 0.f;
#pragma unroll
        for (int n = 0; n < 16; n++) {
            float da = expf(dtv * Ae[n]);
            h[n] = fmaf(da, h[n], dtu * Bv[n]);
            yv = fmaf(h[n], Cv[n], yv);
        }
        y_p[(size_t)i * EE] = f2bf((yv + uv * Dv) * silu_f(zv));
    }
}

// ---------------------------------------------------------------------------
extern "C" void kernel_launch(void* const* d_in, const int* in_sizes, int n_in,
                              void* d_out, int out_size, void* d_ws, size_t ws_size,
                              hipStream_t stream)
{
    const float* x = (const float*)d_in[0];
    const float* ip_w = (const float*)d_in[2];
    const float* ip_b = (const float*)d_in[3];
    const float* ln_w = (const float*)d_in[4];
    const float* ln_b = (const float*)d_in[5];
    const float* inproj_w = (const float*)d_in[6];
    const float* conv_w = (const float*)d_in[7];
    const float* conv_b = (const float*)d_in[8];
    const float* xproj_w = (const float*)d_in[9];
    const float* dtproj_w = (const float*)d_in[10];
    const float* dtproj_b = (const float*)d_in[11];
    const float* A_log = (const float*)d_in[12];
    const float* Dp = (const float*)d_in[13];
    const float* outproj_w = (const float*)d_in[14];
    const float* fnorm_w = (const float*)d_in[15];
    const float* fnorm_b = (const float*)d_in[16];
    const float* op_w = (const float*)d_in[17];
    const float* op_b = (const float*)d_in[18];
    float* out = (float*)d_out;

    const size_t BL = (size_t)BB * LL;   // 2048

    float* fp = (float*)d_ws;
    float* h = fp;           fp += BL * DM_;
    float* xdb = fp;         fp += BL * 96;
    float* dtb = fp;         fp += BL * EE;
    float* Pg = fp;          fp += (size_t)BB * NC * EE * 16;
    float* Sg = fp;          fp += (size_t)BB * NC * EE * 16;
    ushort_t* us = (ushort_t*)fp;
    ushort_t* xb = us;       us += BL * DIN_;
    ushort_t* hnb = us;      us += BL * DM_;
    ushort_t* xzb = us;      us += BL * 2 * EE;
    ushort_t* xm = us;       us += BL * EE;
    ushort_t* xdbb = us;     us += BL * 96;
    ushort_t* yb = us;       us += BL * EE;
    ushort_t* ipwb = us;     us += (size_t)DM_ * DIN_;
    ushort_t* inprojb = us;  us += (size_t)NL_ * 2 * EE * DM_;
    ushort_t* xprojb = us;   us += (size_t)NL_ * 96 * EE;
    ushort_t* dtprojb = us;  us += (size_t)NL_ * EE * RR;
    ushort_t* outprojb = us; us += (size_t)NL_ * DM_ * EE;
    ushort_t* opwb = us;     us += (size_t)DIN_ * DM_;

    dim3 blk(256);
    auto cvt = [&](ushort_t* dst, const float* src, size_t n) {
        int n4 = (int)(n / 4);
        cvt_bf16_kernel<<<dim3((n4 + 255) / 256), blk, 0, stream>>>(dst, src, n4);
    };

    cvt(xb, x, BL * DIN_);
    cvt(ipwb, ip_w, (size_t)DM_ * DIN_);
    cvt(inprojb, inproj_w, (size_t)NL_ * 2 * EE * DM_);
    cvt(xprojb, xproj_w, (size_t)NL_ * 96 * EE);
    cvt(dtprojb, dtproj_w, (size_t)NL_ * EE * RR);
    cvt(outprojb, outproj_w, (size_t)NL_ * DM_ * EE);
    cvt(opwb, op_w, (size_t)DIN_ * DM_);

    // ---- h = ip_b rows; h += x @ ip_w^T  (split-K x2, grid 512)
    rowbias_kernel<<<dim3((int)(BL * DM_ / 4 + 255) / 256), blk, 0, stream>>>(
        h, ip_b, DM_ / 4, (int)(BL * DM_ / 4));
    mgemm_kernel<4, 4, 0><<<dim3(DM_ / 64, BL / 128, 2), blk, 0, stream>>>(
        h, xb, ipwb, nullptr, DM_, DIN_ / 2, DIN_, DIN_, DM_);

    for (int l = 0; l < NL_; l++) {
        layernorm_kernel<<<dim3(BL), blk, 0, stream>>>(hnb, h, ln_w + l * DM_, ln_b + l * DM_);
        // xz = hn @ inproj^T (N=4096, K=1024), grid 512, dbuf
        mgemm_kernel<0, 8, 1><<<dim3(2 * EE / 128, BL / 128), blk, 0, stream>>>(
            xzb, hnb, inprojb + (size_t)l * 2 * EE * DM_, nullptr,
            2 * EE, DM_, DM_, DM_, 2 * EE);
        conv_silu_kernel<<<dim3(EE / 256, LL, BB), blk, 0, stream>>>(
            xm, xzb, conv_w + l * EE * KK, conv_b + l * EE);
        // x_dbl = xm @ xproj^T (N=96): split-K x16
        zero_kernel<<<dim3((int)(BL * 96 / 4 + 255) / 256), blk, 0, stream>>>(xdb, (int)(BL * 96 / 4));
        mgemm_kernel<4, 8, 0><<<dim3(1, BL / 128, 16), blk, 0, stream>>>(
            xdb, xm, xprojb + (size_t)l * 96 * EE, nullptr,
            96, EE / 16, EE, EE, 96);
        cvt(xdbb, xdb, BL * 96);
        // dt = softplus(x_dbl[:, :R] @ dtproj^T + b) (K=64)
        mgemm_kernel<2, 8, 0><<<dim3(EE / 128, BL / 128), blk, 0, stream>>>(
            dtb, xdbb, dtprojb + (size_t)l * EE * RR, dtproj_b + l * EE,
            EE, RR, 96, RR, EE);

        scan_phase1_kernel<<<dim3(EE / 256, NC, BB), blk, 0, stream>>>(
            Pg, Sg, dtb, xm, xdb, A_log + (size_t)l * EE * NN);
        scan_combine_kernel<<<dim3(EE * 16 / 256, BB), blk, 0, stream>>>(Pg, Sg);
        scan_phase2_kernel<<<dim3(EE / 256, NC, BB), blk, 0, stream>>>(
            yb, Pg, dtb, xm, xdb, xzb, A_log + (size_t)l * EE * NN, Dp + l * EE);

        // h += y @ outproj^T : split-K x4 atomicAdd (residual already in h)
        mgemm_kernel<4, 8, 0><<<dim3(DM_ / 128, BL / 128, 4), blk, 0, stream>>>(
            h, yb, outprojb + (size_t)l * DM_ * EE, nullptr,
            DM_, EE / 4, EE, EE, DM_);
    }

    layernorm_kernel<<<dim3(BL), blk, 0, stream>>>(hnb, h, fnorm_w, fnorm_b);
    // out = op_b rows; out += hn @ op_w^T (split-K x4, grid 512)
    rowbias_kernel<<<dim3((int)(BL * DIN_ / 4 + 255) / 256), blk, 0, stream>>>(
        out, op_b, DIN_ / 4, (int)(BL * DIN_ / 4));
    mgemm_kernel<4, 4, 0><<<dim3(DIN_ / 64, BL / 128, 4), blk, 0, stream>>>(
        out, hnb, opwb, nullptr, DIN_, DM_ / 4, DM_, DM_, DIN_);
}

// Round 6
// 1009.687 us; speedup vs baseline: 7.0242x; 1.1782x over previous
//
#include <hip/hip_runtime.h>
#include <math.h>

#define BB 2
#define LL 1024
#define DIN_ 512
#define DM_ 1024
#define NL_ 4
#define EE 2048
#define NN 16
#define RR 64
#define KK 4

#define NC 32   // scan chunks
#define CT 32   // timesteps per chunk (NC*CT == LL)

typedef unsigned short ushort_t;
typedef unsigned int uint_t;

using frag_ab = __attribute__((ext_vector_type(8))) short;
using frag_cd = __attribute__((ext_vector_type(4))) float;

__device__ __forceinline__ float softplus_f(float x) {
    return fmaxf(x, 0.f) + log1pf(expf(-fabsf(x)));
}
__device__ __forceinline__ float silu_fast(float x) {
    return x / (1.f + __expf(-x));
}
__device__ __forceinline__ float bf2f(ushort_t x) {
    return __uint_as_float((uint_t)x << 16);
}
__device__ __forceinline__ ushort_t f2bf(float x) {
    uint_t u = __float_as_uint(x);
    uint_t r = (u + 0x7fffu + ((u >> 16) & 1u)) >> 16;   // RNE
    return (ushort_t)r;
}
__device__ __forceinline__ void gload_lds16(const void* g, void* l) {
    __builtin_amdgcn_global_load_lds(
        (const __attribute__((address_space(1))) void*)g,
        (__attribute__((address_space(3))) void*)l, 16, 0, 0);
}

// ---------------------------------------------------------------------------
// fp32 -> bf16 convert (n multiple of 4)
// ---------------------------------------------------------------------------
__global__ __launch_bounds__(256) void cvt_bf16_kernel(
    ushort_t* __restrict__ o, const float* __restrict__ in, int n4)
{
    int i = blockIdx.x * 256 + threadIdx.x;
    if (i >= n4) return;
    float4 v = ((const float4*)in)[i];
    ushort4 u;
    u.x = f2bf(v.x); u.y = f2bf(v.y); u.z = f2bf(v.z); u.w = f2bf(v.w);
    ((ushort4*)o)[i] = u;
}

__global__ __launch_bounds__(256) void zero_kernel(float* __restrict__ p, int n4)
{
    int i = blockIdx.x * 256 + threadIdx.x;
    if (i < n4) ((float4*)p)[i] = make_float4(0.f, 0.f, 0.f, 0.f);
}

// dst[m, n] = bias[n] for all m
__global__ __launch_bounds__(256) void rowbias_kernel(
    float* __restrict__ dst, const float* __restrict__ bias, int n4, int total4)
{
    int i = blockIdx.x * 256 + threadIdx.x;
    if (i >= total4) return;
    int c = i % n4;
    ((float4*)dst)[i] = ((const float4*)bias)[c];
}

// ---------------------------------------------------------------------------
// bf16 MFMA GEMM with double-buffered LDS staging (verified round 5).
// ---------------------------------------------------------------------------
template <int EPI, int NT, int OUTBF>
__global__ __launch_bounds__(256) void mgemm_kernel(
    void* __restrict__ Cp, const ushort_t* __restrict__ A,
    const ushort_t* __restrict__ W, const float* __restrict__ bias,
    int N, int K, int lda, int ldw, int ldc)
{
    __shared__ __attribute__((aligned(16))) ushort_t As[2][8 * 512];
    __shared__ __attribute__((aligned(16))) ushort_t Bs[2][NT * 512];

    const int tid = threadIdx.x;
    const int w = tid >> 6;
    const int lane = tid & 63;
    const int r = lane & 15;
    const int q = lane >> 4;
    const int m0 = blockIdx.y * 128;
    const int n0 = blockIdx.x * (NT * 16);
    const int wm = w >> 1;
    const int wn = w & 1;
    const int NWT = NT / 2;

    frag_cd acc[4][NWT];
#pragma unroll
    for (int i = 0; i < 4; i++)
#pragma unroll
        for (int j = 0; j < NWT; j++)
#pragma unroll
            for (int t = 0; t < 4; t++) acc[i][j][t] = 0.f;

    size_t koff = (EPI == 4) ? (size_t)blockIdx.z * K : 0;
    const ushort_t* Ab = A + (size_t)m0 * lda + koff;
    const ushort_t* Wb = W + (size_t)n0 * ldw + koff;

    const int NFRAG = 8 + NT;
    auto stage = [&](int k0, int buf) {
        for (int F = w; F < NFRAG; F += 4) {
            if (F < 8) {
                gload_lds16(Ab + (size_t)(F * 16 + r) * lda + k0 + q * 8,
                            &As[buf][F * 512]);
            } else {
                int nt = F - 8;
                if (n0 + nt * 16 + r < N)
                    gload_lds16(Wb + (size_t)(nt * 16 + r) * ldw + k0 + q * 8,
                                &Bs[buf][nt * 512]);
            }
        }
    };

    stage(0, 0);
    int buf = 0;
    for (int k0 = 0; k0 < K; k0 += 32) {
        __syncthreads();
        if (k0 + 32 < K) stage(k0 + 32, buf ^ 1);
        frag_ab af[4], bf[NWT];
#pragma unroll
        for (int i = 0; i < 4; i++)
            af[i] = *(const frag_ab*)(&As[buf][(wm * 4 + i) * 512] + lane * 8);
#pragma unroll
        for (int j = 0; j < NWT; j++)
            bf[j] = *(const frag_ab*)(&Bs[buf][(wn * NWT + j) * 512] + lane * 8);
#pragma unroll
        for (int i = 0; i < 4; i++)
#pragma unroll
            for (int j = 0; j < NWT; j++)
                acc[i][j] = __builtin_amdgcn_mfma_f32_16x16x32_bf16(
                    af[i], bf[j], acc[i][j], 0, 0, 0);
        buf ^= 1;
    }

    float* Cf = (float*)Cp;
    ushort_t* Cb = (ushort_t*)Cp;
#pragma unroll
    for (int i = 0; i < 4; i++) {
        int mrow = m0 + (wm * 4 + i) * 16 + q * 4;
#pragma unroll
        for (int j = 0; j < NWT; j++) {
            int col = n0 + (wn * NWT + j) * 16 + r;
            if (col >= N) continue;
            float bv = (EPI == 1 || EPI == 2) ? bias[col] : 0.f;
#pragma unroll
            for (int t = 0; t < 4; t++) {
                float v = acc[i][j][t];
                size_t idx = (size_t)(mrow + t) * ldc + col;
                if (EPI == 4) { atomicAdd(Cf + idx, v); continue; }
                if (EPI == 1) v += bv;
                if (EPI == 2) v = softplus_f(v + bv);
                if (EPI == 3) v += Cf[idx];
                if (OUTBF) Cb[idx] = f2bf(v);
                else       Cf[idx] = v;
            }
        }
    }
}

// ---------------------------------------------------------------------------
// Row LayerNorm over D=1024 (fp32 in), bf16 out.
// ---------------------------------------------------------------------------
__global__ __launch_bounds__(256) void layernorm_kernel(
    ushort_t* __restrict__ out, const float* __restrict__ in,
    const float* __restrict__ w, const float* __restrict__ b)
{
    const int row = blockIdx.x;
    const int tid = threadIdx.x;
    float4 v = ((const float4*)(in + (size_t)row * DM_))[tid];
    float s = v.x + v.y + v.z + v.w;
    float sq = v.x * v.x + v.y * v.y + v.z * v.z + v.w * v.w;
#pragma unroll
    for (int off = 32; off; off >>= 1) {
        s += __shfl_down(s, off);
        sq += __shfl_down(sq, off);
    }
    __shared__ float ls[4], lq[4];
    int wid = tid >> 6;
    if ((tid & 63) == 0) { ls[wid] = s; lq[wid] = sq; }
    __syncthreads();
    float S = ls[0] + ls[1] + ls[2] + ls[3];
    float Q = lq[0] + lq[1] + lq[2] + lq[3];
    float mean = S * (1.f / DM_);
    float var = Q * (1.f / DM_) - mean * mean;
    float inv = rsqrtf(var + 1e-5f);
    float4 wv = ((const float4*)w)[tid];
    float4 bv = ((const float4*)b)[tid];
    ushort4 o;
    o.x = f2bf((v.x - mean) * inv * wv.x + bv.x);
    o.y = f2bf((v.y - mean) * inv * wv.y + bv.y);
    o.z = f2bf((v.z - mean) * inv * wv.z + bv.z);
    o.w = f2bf((v.w - mean) * inv * wv.w + bv.w);
    ((ushort4*)(out + (size_t)row * DM_))[tid] = o;
}

// ---------------------------------------------------------------------------
// Causal depthwise conv (K=4), 4 timesteps per thread: 7 loads -> 4 outputs.
// grid (E/256, L/4, B)
// ---------------------------------------------------------------------------
__global__ __launch_bounds__(256) void conv_silu_kernel(
    ushort_t* __restrict__ xm, const ushort_t* __restrict__ xz,
    const float* __restrict__ cw, const float* __restrict__ cb)
{
    const int e = blockIdx.x * 256 + threadIdx.x;
    const int t0 = blockIdx.y * 4;
    const int b = blockIdx.z;
    const ushort_t* X = xz + (size_t)b * LL * 2 * EE + e;
    float4 w4 = ((const float4*)cw)[e];
    float wk[4] = {w4.x, w4.y, w4.z, w4.w};
    float cbv = cb[e];
    float v[7];
#pragma unroll
    for (int k = 0; k < 7; k++) {
        int t = t0 - 3 + k;
        v[k] = (t >= 0) ? bf2f(X[(size_t)t * 2 * EE]) : 0.f;
    }
    ushort_t* Y = xm + ((size_t)b * LL + t0) * EE + e;
#pragma unroll
    for (int j = 0; j < 4; j++) {
        float acc = cbv;
#pragma unroll
        for (int k = 0; k < 4; k++) acc = fmaf(wk[k], v[j + k], acc);
        Y[(size_t)j * EE] = f2bf(silu_fast(acc));
    }
}

// ---------------------------------------------------------------------------
// Thread-per-channel chunked scan. __expf fast path; P hoisted via Dsum;
// dt/u(/zg) software-pipelined.
// ---------------------------------------------------------------------------
__global__ __launch_bounds__(256) void scan_phase1_kernel(
    float* __restrict__ Pg, float* __restrict__ Sg,
    const float* __restrict__ dt, const ushort_t* __restrict__ u,
    const float* __restrict__ xdb, const float* __restrict__ A_log)
{
    const int tid = threadIdx.x;
    const int e = blockIdx.x * 256 + tid;
    const int c = blockIdx.y;
    const int b = blockIdx.z;
    const int t0 = c * CT;

    __shared__ float Bs[CT][16];
    {
        int tt = tid >> 3;
        int jj = tid & 7;
        if (jj < 4) {
            float4 v = *(const float4*)(xdb + ((size_t)(b * LL + t0 + tt) * 96 + 64 + jj * 4));
            *(float4*)&Bs[tt][jj * 4] = v;
        }
    }
    __syncthreads();

    float Ae[16];
#pragma unroll
    for (int k = 0; k < 4; k++) {
        float4 a = *(const float4*)(A_log + (size_t)e * NN + k * 4);
        Ae[k * 4 + 0] = -__expf(a.x);
        Ae[k * 4 + 1] = -__expf(a.y);
        Ae[k * 4 + 2] = -__expf(a.z);
        Ae[k * 4 + 3] = -__expf(a.w);
    }

    float S[16];
#pragma unroll
    for (int n = 0; n < 16; n++) S[n] = 0.f;
    float Dsum = 0.f;

    const float* dt_p = dt + (size_t)(b * LL + t0) * EE + e;
    const ushort_t* u_p = u + (size_t)(b * LL + t0) * EE + e;

    float dtv = dt_p[0];
    float uv = bf2f(u_p[0]);
#pragma unroll 4
    for (int i = 0; i < CT; i++) {
        int ip = (i + 1 < CT) ? i + 1 : i;
        float dtn = dt_p[(size_t)ip * EE];
        float un = bf2f(u_p[(size_t)ip * EE]);
        float dtu = dtv * uv;
        Dsum += dtv;
        float Bv[16];
#pragma unroll
        for (int k = 0; k < 4; k++)
            *(float4*)&Bv[k * 4] = *(const float4*)&Bs[i][k * 4];
#pragma unroll
        for (int n = 0; n < 16; n++) {
            float da = __expf(dtv * Ae[n]);
            S[n] = fmaf(da, S[n], dtu * Bv[n]);
        }
        dtv = dtn; uv = un;
    }

    size_t o = ((size_t)(b * NC + c) * EE + e) * 16;
#pragma unroll
    for (int k = 0; k < 4; k++) {
        float4 p4;
        p4.x = __expf(Dsum * Ae[k * 4 + 0]);
        p4.y = __expf(Dsum * Ae[k * 4 + 1]);
        p4.z = __expf(Dsum * Ae[k * 4 + 2]);
        p4.w = __expf(Dsum * Ae[k * 4 + 3]);
        *(float4*)(Pg + o + k * 4) = p4;
        *(float4*)(Sg + o + k * 4) = *(float4*)&S[k * 4];
    }
}

__global__ __launch_bounds__(256) void scan_combine_kernel(
    float* __restrict__ Pg, const float* __restrict__ Sg)
{
    const int f = blockIdx.x * 256 + threadIdx.x;
    const int b = blockIdx.y;
    float h = 0.f;
    for (int c = 0; c < NC; c++) {
        size_t o = (size_t)(b * NC + c) * EE * 16 + f;
        float p = Pg[o];
        float s = Sg[o];
        h = fmaf(p, h, s);
        Pg[o] = h;
    }
}

__global__ __launch_bounds__(256) void scan_phase2_kernel(
    ushort_t* __restrict__ y, const float* __restrict__ Pg,
    const float* __restrict__ dt, const ushort_t* __restrict__ u,
    const float* __restrict__ xdb, const ushort_t* __restrict__ xz,
    const float* __restrict__ A_log, const float* __restrict__ Dp)
{
    const int tid = threadIdx.x;
    const int e = blockIdx.x * 256 + tid;
    const int c = blockIdx.y;
    const int b = blockIdx.z;
    const int t0 = c * CT;

    __shared__ float Bs[CT][16], Cs[CT][16];
    {
        int tt = tid >> 3;
        int jj = tid & 7;
        float4 v = *(const float4*)(xdb + ((size_t)(b * LL + t0 + tt) * 96 + 64 + jj * 4));
        if (jj < 4) *(float4*)&Bs[tt][jj * 4] = v;
        else        *(float4*)&Cs[tt][(jj - 4) * 4] = v;
    }
    __syncthreads();

    float Ae[16];
#pragma unroll
    for (int k = 0; k < 4; k++) {
        float4 a = *(const float4*)(A_log + (size_t)e * NN + k * 4);
        Ae[k * 4 + 0] = -__expf(a.x);
        Ae[k * 4 + 1] = -__expf(a.y);
        Ae[k * 4 + 2] = -__expf(a.z);
        Ae[k * 4 + 3] = -__expf(a.w);
    }

    float h[16];
    if (c == 0) {
#pragma unroll
        for (int n = 0; n < 16; n++) h[n] = 0.f;
    } else {
        size_t o = ((size_t)(b * NC + (c - 1)) * EE + e) * 16;
#pragma unroll
        for (int k = 0; k < 4; k++)
            *(float4*)&h[k * 4] = *(const float4*)(Pg + o + k * 4);
    }

    const float Dv = Dp[e];
    const float* dt_p = dt + (size_t)(b * LL + t0) * EE + e;
    const ushort_t* u_p = u + (size_t)(b * LL + t0) * EE + e;
    const ushort_t* zg_p = xz + (size_t)(b * LL + t0) * 2 * EE + EE + e;
    ushort_t* y_p = y + (size_t)(b * LL + t0) * EE + e;

    float dtv = dt_p[0];
    float uv = bf2f(u_p[0]);
    float zv = bf2f(zg_p[0]);
#pragma unroll 4
    for (int i = 0; i < CT; i++) {
        int ip = (i + 1 < CT) ? i + 1 : i;
        float dtn = dt_p[(size_t)ip * EE];
        float un = bf2f(u_p[(size_t)ip * EE]);
        float zn = bf2f(zg_p[(size_t)ip * 2 * EE]);
        float dtu = dtv * uv;
        float Bv[16], Cv[16];
#pragma unroll
        for (int k = 0; k < 4; k++) {
            *(float4*)&Bv[k * 4] = *(const float4*)&Bs[i][k * 4];
            *(float4*)&Cv[k * 4] = *(const float4*)&Cs[i][k * 4];
        }
        float yv = 0.f;
#pragma unroll
        for (int n = 0; n < 16; n++) {
            float da = __expf(dtv * Ae[n]);
            h[n] = fmaf(da, h[n], dtu * Bv[n]);
            yv = fmaf(h[n], Cv[n], yv);
        }
        y_p[(size_t)i * EE] = f2bf((yv + uv * Dv) * silu_fast(zv));
        dtv = dtn; uv = un; zv = zn;
    }
}

// ---------------------------------------------------------------------------
extern "C" void kernel_launch(void* const* d_in, const int* in_sizes, int n_in,
                              void* d_out, int out_size, void* d_ws, size_t ws_size,
                              hipStream_t stream)
{
    const float* x = (const float*)d_in[0];
    const float* ip_w = (const float*)d_in[2];
    const float* ip_b = (const float*)d_in[3];
    const float* ln_w = (const float*)d_in[4];
    const float* ln_b = (const float*)d_in[5];
    const float* inproj_w = (const float*)d_in[6];
    const float* conv_w = (const float*)d_in[7];
    const float* conv_b = (const float*)d_in[8];
    const float* xproj_w = (const float*)d_in[9];
    const float* dtproj_w = (const float*)d_in[10];
    const float* dtproj_b = (const float*)d_in[11];
    const float* A_log = (const float*)d_in[12];
    const float* Dp = (const float*)d_in[13];
    const float* outproj_w = (const float*)d_in[14];
    const float* fnorm_w = (const float*)d_in[15];
    const float* fnorm_b = (const float*)d_in[16];
    const float* op_w = (const float*)d_in[17];
    const float* op_b = (const float*)d_in[18];
    float* out = (float*)d_out;

    const size_t BL = (size_t)BB * LL;   // 2048

    float* fp = (float*)d_ws;
    float* h = fp;           fp += BL * DM_;
    float* xdb = fp;         fp += BL * 96;
    float* dtb = fp;         fp += BL * EE;
    float* Pg = fp;          fp += (size_t)BB * NC * EE * 16;
    float* Sg = fp;          fp += (size_t)BB * NC * EE * 16;
    ushort_t* us = (ushort_t*)fp;
    ushort_t* xb = us;       us += BL * DIN_;
    ushort_t* hnb = us;      us += BL * DM_;
    ushort_t* xzb = us;      us += BL * 2 * EE;
    ushort_t* xm = us;       us += BL * EE;
    ushort_t* xdbb = us;     us += BL * 96;
    ushort_t* yb = us;       us += BL * EE;
    ushort_t* ipwb = us;     us += (size_t)DM_ * DIN_;
    ushort_t* inprojb = us;  us += (size_t)NL_ * 2 * EE * DM_;
    ushort_t* xprojb = us;   us += (size_t)NL_ * 96 * EE;
    ushort_t* dtprojb = us;  us += (size_t)NL_ * EE * RR;
    ushort_t* outprojb = us; us += (size_t)NL_ * DM_ * EE;
    ushort_t* opwb = us;     us += (size_t)DIN_ * DM_;

    dim3 blk(256);
    auto cvt = [&](ushort_t* dst, const float* src, size_t n) {
        int n4 = (int)(n / 4);
        cvt_bf16_kernel<<<dim3((n4 + 255) / 256), blk, 0, stream>>>(dst, src, n4);
    };

    cvt(xb, x, BL * DIN_);
    cvt(ipwb, ip_w, (size_t)DM_ * DIN_);
    cvt(inprojb, inproj_w, (size_t)NL_ * 2 * EE * DM_);
    cvt(xprojb, xproj_w, (size_t)NL_ * 96 * EE);
    cvt(dtprojb, dtproj_w, (size_t)NL_ * EE * RR);
    cvt(outprojb, outproj_w, (size_t)NL_ * DM_ * EE);
    cvt(opwb, op_w, (size_t)DIN_ * DM_);

    // ---- h = ip_b rows; h += x @ ip_w^T  (split-K x2, grid 512)
    rowbias_kernel<<<dim3((int)(BL * DM_ / 4 + 255) / 256), blk, 0, stream>>>(
        h, ip_b, DM_ / 4, (int)(BL * DM_ / 4));
    mgemm_kernel<4, 4, 0><<<dim3(DM_ / 64, BL / 128, 2), blk, 0, stream>>>(
        h, xb, ipwb, nullptr, DM_, DIN_ / 2, DIN_, DIN_, DM_);

    for (int l = 0; l < NL_; l++) {
        layernorm_kernel<<<dim3(BL), blk, 0, stream>>>(hnb, h, ln_w + l * DM_, ln_b + l * DM_);
        mgemm_kernel<0, 8, 1><<<dim3(2 * EE / 128, BL / 128), blk, 0, stream>>>(
            xzb, hnb, inprojb + (size_t)l * 2 * EE * DM_, nullptr,
            2 * EE, DM_, DM_, DM_, 2 * EE);
        conv_silu_kernel<<<dim3(EE / 256, LL / 4, BB), blk, 0, stream>>>(
            xm, xzb, conv_w + l * EE * KK, conv_b + l * EE);
        zero_kernel<<<dim3((int)(BL * 96 / 4 + 255) / 256), blk, 0, stream>>>(xdb, (int)(BL * 96 / 4));
        mgemm_kernel<4, 8, 0><<<dim3(1, BL / 128, 16), blk, 0, stream>>>(
            xdb, xm, xprojb + (size_t)l * 96 * EE, nullptr,
            96, EE / 16, EE, EE, 96);
        cvt(xdbb, xdb, BL * 96);
        mgemm_kernel<2, 8, 0><<<dim3(EE / 128, BL / 128), blk, 0, stream>>>(
            dtb, xdbb, dtprojb + (size_t)l * EE * RR, dtproj_b + l * EE,
            EE, RR, 96, RR, EE);

        scan_phase1_kernel<<<dim3(EE / 256, NC, BB), blk, 0, stream>>>(
            Pg, Sg, dtb, xm, xdb, A_log + (size_t)l * EE * NN);
        scan_combine_kernel<<<dim3(EE * 16 / 256, BB), blk, 0, stream>>>(Pg, Sg);
        scan_phase2_kernel<<<dim3(EE / 256, NC, BB), blk, 0, stream>>>(
            yb, Pg, dtb, xm, xdb, xzb, A_log + (size_t)l * EE * NN, Dp + l * EE);

        mgemm_kernel<4, 8, 0><<<dim3(DM_ / 128, BL / 128, 4), blk, 0, stream>>>(
            h, yb, outprojb + (size_t)l * DM_ * EE, nullptr,
            DM_, EE / 4, EE, EE, DM_);
    }

    layernorm_kernel<<<dim3(BL), blk, 0, stream>>>(hnb, h, fnorm_w, fnorm_b);
    rowbias_kernel<<<dim3((int)(BL * DIN_ / 4 + 255) / 256), blk, 0, stream>>>(
        out, op_b, DIN_ / 4, (int)(BL * DIN_ / 4));
    mgemm_kernel<4, 4, 0><<<dim3(DIN_ / 64, BL / 128, 4), blk, 0, stream>>>(
        out, hnb, opwb, nullptr, DIN_, DM_ / 4, DM_, DM_, DIN_);
}

// Round 7
// 917.943 us; speedup vs baseline: 7.7262x; 1.0999x over previous
//
#include <hip/hip_runtime.h>
#include <math.h>

#define BB 2
#define LL 1024
#define DIN_ 512
#define DM_ 1024
#define NL_ 4
#define EE 2048
#define NN 16
#define RR 64
#define KK 4

#define NC 32   // scan chunks
#define CT 32   // timesteps per chunk (NC*CT == LL)

typedef unsigned short ushort_t;
typedef unsigned int uint_t;

using frag_ab = __attribute__((ext_vector_type(8))) short;
using frag_cd = __attribute__((ext_vector_type(4))) float;

__device__ __forceinline__ float softplus_f(float x) {
    return fmaxf(x, 0.f) + log1pf(expf(-fabsf(x)));
}
__device__ __forceinline__ float silu_fast(float x) {
    return x / (1.f + __expf(-x));
}
__device__ __forceinline__ float bf2f(ushort_t x) {
    return __uint_as_float((uint_t)x << 16);
}
__device__ __forceinline__ ushort_t f2bf(float x) {
    uint_t u = __float_as_uint(x);
    uint_t r = (u + 0x7fffu + ((u >> 16) & 1u)) >> 16;   // RNE
    return (ushort_t)r;
}
__device__ __forceinline__ void gload_lds16(const void* g, void* l) {
    __builtin_amdgcn_global_load_lds(
        (const __attribute__((address_space(1))) void*)g,
        (__attribute__((address_space(3))) void*)l, 16, 0, 0);
}

// ---------------------------------------------------------------------------
// fp32 -> bf16 convert (n multiple of 4)
// ---------------------------------------------------------------------------
__global__ __launch_bounds__(256) void cvt_bf16_kernel(
    ushort_t* __restrict__ o, const float* __restrict__ in, int n4)
{
    int i = blockIdx.x * 256 + threadIdx.x;
    if (i >= n4) return;
    float4 v = ((const float4*)in)[i];
    ushort4 u;
    u.x = f2bf(v.x); u.y = f2bf(v.y); u.z = f2bf(v.z); u.w = f2bf(v.w);
    ((ushort4*)o)[i] = u;
}

// ---------------------------------------------------------------------------
// bf16 MFMA GEMM, double-buffered LDS staging.
// EPI: 0 none, 2 softplus(+bias), 5 split-K partial store
//      (blockIdx.z picks K-chunk; partial z at Cf + z*pstride)
// ---------------------------------------------------------------------------
template <int EPI, int NT, int OUTBF>
__global__ __launch_bounds__(256) void mgemm_kernel(
    void* __restrict__ Cp, const ushort_t* __restrict__ A,
    const ushort_t* __restrict__ W, const float* __restrict__ bias,
    int N, int K, int lda, int ldw, int ldc, int pstride)
{
    __shared__ __attribute__((aligned(16))) ushort_t As[2][8 * 512];
    __shared__ __attribute__((aligned(16))) ushort_t Bs[2][NT * 512];

    const int tid = threadIdx.x;
    const int w = tid >> 6;
    const int lane = tid & 63;
    const int r = lane & 15;
    const int q = lane >> 4;
    const int m0 = blockIdx.y * 128;
    const int n0 = blockIdx.x * (NT * 16);
    const int wm = w >> 1;
    const int wn = w & 1;
    const int NWT = NT / 2;

    frag_cd acc[4][NWT];
#pragma unroll
    for (int i = 0; i < 4; i++)
#pragma unroll
        for (int j = 0; j < NWT; j++)
#pragma unroll
            for (int t = 0; t < 4; t++) acc[i][j][t] = 0.f;

    size_t koff = (EPI == 5) ? (size_t)blockIdx.z * K : 0;
    const ushort_t* Ab = A + (size_t)m0 * lda + koff;
    const ushort_t* Wb = W + (size_t)n0 * ldw + koff;

    const int NFRAG = 8 + NT;
    auto stage = [&](int k0, int buf) {
        for (int F = w; F < NFRAG; F += 4) {
            if (F < 8) {
                gload_lds16(Ab + (size_t)(F * 16 + r) * lda + k0 + q * 8,
                            &As[buf][F * 512]);
            } else {
                int nt = F - 8;
                if (n0 + nt * 16 + r < N)
                    gload_lds16(Wb + (size_t)(nt * 16 + r) * ldw + k0 + q * 8,
                                &Bs[buf][nt * 512]);
            }
        }
    };

    stage(0, 0);
    int buf = 0;
    for (int k0 = 0; k0 < K; k0 += 32) {
        __syncthreads();
        if (k0 + 32 < K) stage(k0 + 32, buf ^ 1);
        frag_ab af[4], bf[NWT];
#pragma unroll
        for (int i = 0; i < 4; i++)
            af[i] = *(const frag_ab*)(&As[buf][(wm * 4 + i) * 512] + lane * 8);
#pragma unroll
        for (int j = 0; j < NWT; j++)
            bf[j] = *(const frag_ab*)(&Bs[buf][(wn * NWT + j) * 512] + lane * 8);
#pragma unroll
        for (int i = 0; i < 4; i++)
#pragma unroll
            for (int j = 0; j < NWT; j++)
                acc[i][j] = __builtin_amdgcn_mfma_f32_16x16x32_bf16(
                    af[i], bf[j], acc[i][j], 0, 0, 0);
        buf ^= 1;
    }

    float* Cf = (float*)Cp;
    ushort_t* Cb = (ushort_t*)Cp;
    float* Cpart = (EPI == 5) ? Cf + (size_t)blockIdx.z * pstride : Cf;
#pragma unroll
    for (int i = 0; i < 4; i++) {
        int mrow = m0 + (wm * 4 + i) * 16 + q * 4;
#pragma unroll
        for (int j = 0; j < NWT; j++) {
            int col = n0 + (wn * NWT + j) * 16 + r;
            if (col >= N) continue;
            float bv = (EPI == 2) ? bias[col] : 0.f;
#pragma unroll
            for (int t = 0; t < 4; t++) {
                float v = acc[i][j][t];
                size_t idx = (size_t)(mrow + t) * ldc + col;
                if (EPI == 5) { Cpart[idx] = v; continue; }
                if (EPI == 2) v = softplus_f(v + bv);
                if (OUTBF) Cb[idx] = f2bf(v);
                else       Cf[idx] = v;
            }
        }
    }
}

// ---------------------------------------------------------------------------
// Fused split-K reduce + optional residual/bias + LayerNorm (D=1024).
// One block per row. h' = (hasres? h:0) + sum_p parts[p] + (bias? bias:0);
// writes h' (fp32) and LN(h') (bf16).
// ---------------------------------------------------------------------------
__global__ __launch_bounds__(256) void reduce_ln_kernel(
    float* __restrict__ h, ushort_t* __restrict__ hn,
    const float* __restrict__ parts, int nparts, int pstride4,
    const float* __restrict__ bias,
    const float* __restrict__ w, const float* __restrict__ b, int hasres)
{
    const int row = blockIdx.x;
    const int tid = threadIdx.x;
    const int i4 = row * (DM_ / 4) + tid;

    float4 v = make_float4(0.f, 0.f, 0.f, 0.f);
    if (hasres) v = ((const float4*)h)[i4];
    for (int p = 0; p < nparts; p++) {
        float4 t = ((const float4*)parts)[(size_t)p * pstride4 + i4];
        v.x += t.x; v.y += t.y; v.z += t.z; v.w += t.w;
    }
    if (bias) {
        float4 t = ((const float4*)bias)[tid];
        v.x += t.x; v.y += t.y; v.z += t.z; v.w += t.w;
    }
    ((float4*)h)[i4] = v;

    float s = v.x + v.y + v.z + v.w;
    float sq = v.x * v.x + v.y * v.y + v.z * v.z + v.w * v.w;
#pragma unroll
    for (int off = 32; off; off >>= 1) {
        s += __shfl_down(s, off);
        sq += __shfl_down(sq, off);
    }
    __shared__ float ls[4], lq[4];
    int wid = tid >> 6;
    if ((tid & 63) == 0) { ls[wid] = s; lq[wid] = sq; }
    __syncthreads();
    float S = ls[0] + ls[1] + ls[2] + ls[3];
    float Q = lq[0] + lq[1] + lq[2] + lq[3];
    float mean = S * (1.f / DM_);
    float var = Q * (1.f / DM_) - mean * mean;
    float inv = rsqrtf(var + 1e-5f);
    float4 wv = ((const float4*)w)[tid];
    float4 bv = ((const float4*)b)[tid];
    ushort4 o;
    o.x = f2bf((v.x - mean) * inv * wv.x + bv.x);
    o.y = f2bf((v.y - mean) * inv * wv.y + bv.y);
    o.z = f2bf((v.z - mean) * inv * wv.z + bv.z);
    o.w = f2bf((v.w - mean) * inv * wv.w + bv.w);
    ((ushort4*)hn)[i4] = o;
}

// xdb = sum of 16 xproj partials; writes fp32 + bf16 copies.
__global__ __launch_bounds__(256) void reduce_xdb_kernel(
    float* __restrict__ xdb, ushort_t* __restrict__ xdbb,
    const float* __restrict__ parts, int pstride4, int total4)
{
    int i = blockIdx.x * 256 + threadIdx.x;
    if (i >= total4) return;
    float4 v = make_float4(0.f, 0.f, 0.f, 0.f);
#pragma unroll
    for (int p = 0; p < 16; p++) {
        float4 t = ((const float4*)parts)[(size_t)p * pstride4 + i];
        v.x += t.x; v.y += t.y; v.z += t.z; v.w += t.w;
    }
    ((float4*)xdb)[i] = v;
    ushort4 u;
    u.x = f2bf(v.x); u.y = f2bf(v.y); u.z = f2bf(v.z); u.w = f2bf(v.w);
    ((ushort4*)xdbb)[i] = u;
}

// out = sum of 4 partials + bias (final op projection)
__global__ __launch_bounds__(256) void reduce_bias_kernel(
    float* __restrict__ out, const float* __restrict__ parts,
    const float* __restrict__ bias, int pstride4, int n4, int total4)
{
    int i = blockIdx.x * 256 + threadIdx.x;
    if (i >= total4) return;
    float4 v = ((const float4*)bias)[i % n4];
#pragma unroll
    for (int p = 0; p < 4; p++) {
        float4 t = ((const float4*)parts)[(size_t)p * pstride4 + i];
        v.x += t.x; v.y += t.y; v.z += t.z; v.w += t.w;
    }
    ((float4*)out)[i] = v;
}

// ---------------------------------------------------------------------------
// Causal depthwise conv (K=4), 4 timesteps per thread.
// ---------------------------------------------------------------------------
__global__ __launch_bounds__(256) void conv_silu_kernel(
    ushort_t* __restrict__ xm, const ushort_t* __restrict__ xz,
    const float* __restrict__ cw, const float* __restrict__ cb)
{
    const int e = blockIdx.x * 256 + threadIdx.x;
    const int t0 = blockIdx.y * 4;
    const int b = blockIdx.z;
    const ushort_t* X = xz + (size_t)b * LL * 2 * EE + e;
    float4 w4 = ((const float4*)cw)[e];
    float wk[4] = {w4.x, w4.y, w4.z, w4.w};
    float cbv = cb[e];
    float v[7];
#pragma unroll
    for (int k = 0; k < 7; k++) {
        int t = t0 - 3 + k;
        v[k] = (t >= 0) ? bf2f(X[(size_t)t * 2 * EE]) : 0.f;
    }
    ushort_t* Y = xm + ((size_t)b * LL + t0) * EE + e;
#pragma unroll
    for (int j = 0; j < 4; j++) {
        float acc = cbv;
#pragma unroll
        for (int k = 0; k < 4; k++) acc = fmaf(wk[k], v[j + k], acc);
        Y[(size_t)j * EE] = f2bf(silu_fast(acc));
    }
}

// ---------------------------------------------------------------------------
// Thread-per-channel chunked scan (verified rounds 4-6).
// ---------------------------------------------------------------------------
__global__ __launch_bounds__(256) void scan_phase1_kernel(
    float* __restrict__ Pg, float* __restrict__ Sg,
    const float* __restrict__ dt, const ushort_t* __restrict__ u,
    const float* __restrict__ xdb, const float* __restrict__ A_log)
{
    const int tid = threadIdx.x;
    const int e = blockIdx.x * 256 + tid;
    const int c = blockIdx.y;
    const int b = blockIdx.z;
    const int t0 = c * CT;

    __shared__ float Bs[CT][16];
    {
        int tt = tid >> 3;
        int jj = tid & 7;
        if (jj < 4) {
            float4 v = *(const float4*)(xdb + ((size_t)(b * LL + t0 + tt) * 96 + 64 + jj * 4));
            *(float4*)&Bs[tt][jj * 4] = v;
        }
    }
    __syncthreads();

    float Ae[16];
#pragma unroll
    for (int k = 0; k < 4; k++) {
        float4 a = *(const float4*)(A_log + (size_t)e * NN + k * 4);
        Ae[k * 4 + 0] = -__expf(a.x);
        Ae[k * 4 + 1] = -__expf(a.y);
        Ae[k * 4 + 2] = -__expf(a.z);
        Ae[k * 4 + 3] = -__expf(a.w);
    }

    float S[16];
#pragma unroll
    for (int n = 0; n < 16; n++) S[n] = 0.f;
    float Dsum = 0.f;

    const float* dt_p = dt + (size_t)(b * LL + t0) * EE + e;
    const ushort_t* u_p = u + (size_t)(b * LL + t0) * EE + e;

    float dtv = dt_p[0];
    float uv = bf2f(u_p[0]);
#pragma unroll 4
    for (int i = 0; i < CT; i++) {
        int ip = (i + 1 < CT) ? i + 1 : i;
        float dtn = dt_p[(size_t)ip * EE];
        float un = bf2f(u_p[(size_t)ip * EE]);
        float dtu = dtv * uv;
        Dsum += dtv;
        float Bv[16];
#pragma unroll
        for (int k = 0; k < 4; k++)
            *(float4*)&Bv[k * 4] = *(const float4*)&Bs[i][k * 4];
#pragma unroll
        for (int n = 0; n < 16; n++) {
            float da = __expf(dtv * Ae[n]);
            S[n] = fmaf(da, S[n], dtu * Bv[n]);
        }
        dtv = dtn; uv = un;
    }

    size_t o = ((size_t)(b * NC + c) * EE + e) * 16;
#pragma unroll
    for (int k = 0; k < 4; k++) {
        float4 p4;
        p4.x = __expf(Dsum * Ae[k * 4 + 0]);
        p4.y = __expf(Dsum * Ae[k * 4 + 1]);
        p4.z = __expf(Dsum * Ae[k * 4 + 2]);
        p4.w = __expf(Dsum * Ae[k * 4 + 3]);
        *(float4*)(Pg + o + k * 4) = p4;
        *(float4*)(Sg + o + k * 4) = *(float4*)&S[k * 4];
    }
}

__global__ __launch_bounds__(256) void scan_combine_kernel(
    float* __restrict__ Pg, const float* __restrict__ Sg)
{
    const int f = blockIdx.x * 256 + threadIdx.x;
    const int b = blockIdx.y;
    float h = 0.f;
    for (int c = 0; c < NC; c++) {
        size_t o = (size_t)(b * NC + c) * EE * 16 + f;
        float p = Pg[o];
        float s = Sg[o];
        h = fmaf(p, h, s);
        Pg[o] = h;
    }
}

__global__ __launch_bounds__(256) void scan_phase2_kernel(
    ushort_t* __restrict__ y, const float* __restrict__ Pg,
    const float* __restrict__ dt, const ushort_t* __restrict__ u,
    const float* __restrict__ xdb, const ushort_t* __restrict__ xz,
    const float* __restrict__ A_log, const float* __restrict__ Dp)
{
    const int tid = threadIdx.x;
    const int e = blockIdx.x * 256 + tid;
    const int c = blockIdx.y;
    const int b = blockIdx.z;
    const int t0 = c * CT;

    __shared__ float Bs[CT][16], Cs[CT][16];
    {
        int tt = tid >> 3;
        int jj = tid & 7;
        float4 v = *(const float4*)(xdb + ((size_t)(b * LL + t0 + tt) * 96 + 64 + jj * 4));
        if (jj < 4) *(float4*)&Bs[tt][jj * 4] = v;
        else        *(float4*)&Cs[tt][(jj - 4) * 4] = v;
    }
    __syncthreads();

    float Ae[16];
#pragma unroll
    for (int k = 0; k < 4; k++) {
        float4 a = *(const float4*)(A_log + (size_t)e * NN + k * 4);
        Ae[k * 4 + 0] = -__expf(a.x);
        Ae[k * 4 + 1] = -__expf(a.y);
        Ae[k * 4 + 2] = -__expf(a.z);
        Ae[k * 4 + 3] = -__expf(a.w);
    }

    float h[16];
    if (c == 0) {
#pragma unroll
        for (int n = 0; n < 16; n++) h[n] = 0.f;
    } else {
        size_t o = ((size_t)(b * NC + (c - 1)) * EE + e) * 16;
#pragma unroll
        for (int k = 0; k < 4; k++)
            *(float4*)&h[k * 4] = *(const float4*)(Pg + o + k * 4);
    }

    const float Dv = Dp[e];
    const float* dt_p = dt + (size_t)(b * LL + t0) * EE + e;
    const ushort_t* u_p = u + (size_t)(b * LL + t0) * EE + e;
    const ushort_t* zg_p = xz + (size_t)(b * LL + t0) * 2 * EE + EE + e;
    ushort_t* y_p = y + (size_t)(b * LL + t0) * EE + e;

    float dtv = dt_p[0];
    float uv = bf2f(u_p[0]);
    float zv = bf2f(zg_p[0]);
#pragma unroll 4
    for (int i = 0; i < CT; i++) {
        int ip = (i + 1 < CT) ? i + 1 : i;
        float dtn = dt_p[(size_t)ip * EE];
        float un = bf2f(u_p[(size_t)ip * EE]);
        float zn = bf2f(zg_p[(size_t)ip * 2 * EE]);
        float dtu = dtv * uv;
        float Bv[16], Cv[16];
#pragma unroll
        for (int k = 0; k < 4; k++) {
            *(float4*)&Bv[k * 4] = *(const float4*)&Bs[i][k * 4];
            *(float4*)&Cv[k * 4] = *(const float4*)&Cs[i][k * 4];
        }
        float yv = 0.f;
#pragma unroll
        for (int n = 0; n < 16; n++) {
            float da = __expf(dtv * Ae[n]);
            h[n] = fmaf(da, h[n], dtu * Bv[n]);
            yv = fmaf(h[n], Cv[n], yv);
        }
        y_p[(size_t)i * EE] = f2bf((yv + uv * Dv) * silu_fast(zv));
        dtv = dtn; uv = un; zv = zn;
    }
}

// ---------------------------------------------------------------------------
extern "C" void kernel_launch(void* const* d_in, const int* in_sizes, int n_in,
                              void* d_out, int out_size, void* d_ws, size_t ws_size,
                              hipStream_t stream)
{
    const float* x = (const float*)d_in[0];
    const float* ip_w = (const float*)d_in[2];
    const float* ip_b = (const float*)d_in[3];
    const float* ln_w = (const float*)d_in[4];
    const float* ln_b = (const float*)d_in[5];
    const float* inproj_w = (const float*)d_in[6];
    const float* conv_w = (const float*)d_in[7];
    const float* conv_b = (const float*)d_in[8];
    const float* xproj_w = (const float*)d_in[9];
    const float* dtproj_w = (const float*)d_in[10];
    const float* dtproj_b = (const float*)d_in[11];
    const float* A_log = (const float*)d_in[12];
    const float* Dp = (const float*)d_in[13];
    const float* outproj_w = (const float*)d_in[14];
    const float* fnorm_w = (const float*)d_in[15];
    const float* fnorm_b = (const float*)d_in[16];
    const float* op_w = (const float*)d_in[17];
    const float* op_b = (const float*)d_in[18];
    float* out = (float*)d_out;

    const size_t BL = (size_t)BB * LL;   // 2048

    float* fp = (float*)d_ws;
    float* h = fp;           fp += BL * DM_;
    float* xdb = fp;         fp += BL * 96;
    float* dtb = fp;         fp += BL * EE;            // also: parts region base
    float* Pg = fp;          fp += (size_t)BB * NC * EE * 16;
    float* Sg = fp;          fp += (size_t)BB * NC * EE * 16;
    // Partial buffers overlay dtb..Sg (8M floats): dead whenever partials live.
    float* parts = dtb;
    ushort_t* us = (ushort_t*)fp;
    ushort_t* xb = us;       us += BL * DIN_;
    ushort_t* hnb = us;      us += BL * DM_;
    ushort_t* xzb = us;      us += BL * 2 * EE;
    ushort_t* xm = us;       us += BL * EE;
    ushort_t* xdbb = us;     us += BL * 96;
    ushort_t* yb = us;       us += BL * EE;
    ushort_t* ipwb = us;     us += (size_t)DM_ * DIN_;
    ushort_t* inprojb = us;  us += (size_t)NL_ * 2 * EE * DM_;
    ushort_t* xprojb = us;   us += (size_t)NL_ * 96 * EE;
    ushort_t* dtprojb = us;  us += (size_t)NL_ * EE * RR;
    ushort_t* outprojb = us; us += (size_t)NL_ * DM_ * EE;
    ushort_t* opwb = us;     us += (size_t)DIN_ * DM_;

    dim3 blk(256);
    auto cvt = [&](ushort_t* dst, const float* src, size_t n) {
        int n4 = (int)(n / 4);
        cvt_bf16_kernel<<<dim3((n4 + 255) / 256), blk, 0, stream>>>(dst, src, n4);
    };

    cvt(xb, x, BL * DIN_);
    cvt(ipwb, ip_w, (size_t)DM_ * DIN_);
    cvt(inprojb, inproj_w, (size_t)NL_ * 2 * EE * DM_);
    cvt(xprojb, xproj_w, (size_t)NL_ * 96 * EE);
    cvt(dtprojb, dtproj_w, (size_t)NL_ * EE * RR);
    cvt(outprojb, outproj_w, (size_t)NL_ * DM_ * EE);
    cvt(opwb, op_w, (size_t)DIN_ * DM_);

    const int PS_DM = (int)(BL * DM_);    // partial stride, DM-wide outputs

    // ---- ip: partials x2, then fused reduce(+ip_b) + LN[0]
    mgemm_kernel<5, 4, 0><<<dim3(DM_ / 64, BL / 128, 2), blk, 0, stream>>>(
        parts, xb, ipwb, nullptr, DM_, DIN_ / 2, DIN_, DIN_, DM_, PS_DM);
    reduce_ln_kernel<<<dim3(BL), blk, 0, stream>>>(
        h, hnb, parts, 2, PS_DM / 4, ip_b, ln_w, ln_b, 0);

    for (int l = 0; l < NL_; l++) {
        // xz = hn @ inproj^T (N=4096, K=1024), grid 512, dbuf
        mgemm_kernel<0, 8, 1><<<dim3(2 * EE / 128, BL / 128), blk, 0, stream>>>(
            xzb, hnb, inprojb + (size_t)l * 2 * EE * DM_, nullptr,
            2 * EE, DM_, DM_, DM_, 2 * EE, 0);
        conv_silu_kernel<<<dim3(EE / 256, LL / 4, BB), blk, 0, stream>>>(
            xm, xzb, conv_w + l * EE * KK, conv_b + l * EE);
        // x_dbl partials x16 -> fused reduce (fp32 + bf16)
        mgemm_kernel<5, 8, 0><<<dim3(1, BL / 128, 16), blk, 0, stream>>>(
            parts, xm, xprojb + (size_t)l * 96 * EE, nullptr,
            96, EE / 16, EE, EE, 96, (int)(BL * 96));
        reduce_xdb_kernel<<<dim3((int)(BL * 96 / 4 + 255) / 256), blk, 0, stream>>>(
            xdb, xdbb, parts, (int)(BL * 96 / 4), (int)(BL * 96 / 4));
        // dt = softplus(x_dbl[:, :R] @ dtproj^T + b) (K=64)
        mgemm_kernel<2, 8, 0><<<dim3(EE / 128, BL / 128), blk, 0, stream>>>(
            dtb, xdbb, dtprojb + (size_t)l * EE * RR, dtproj_b + l * EE,
            EE, RR, 96, RR, EE, 0);

        scan_phase1_kernel<<<dim3(EE / 256, NC, BB), blk, 0, stream>>>(
            Pg, Sg, dtb, xm, xdb, A_log + (size_t)l * EE * NN);
        scan_combine_kernel<<<dim3(EE * 16 / 256, BB), blk, 0, stream>>>(Pg, Sg);
        scan_phase2_kernel<<<dim3(EE / 256, NC, BB), blk, 0, stream>>>(
            yb, Pg, dtb, xm, xdb, xzb, A_log + (size_t)l * EE * NN, Dp + l * EE);

        // outproj partials x4 (overlays dtb/Pg/Sg - all dead now), then
        // fused reduce + residual + next LN (or final fnorm)
        mgemm_kernel<5, 8, 0><<<dim3(DM_ / 128, BL / 128, 4), blk, 0, stream>>>(
            parts, yb, outprojb + (size_t)l * DM_ * EE, nullptr,
            DM_, EE / 4, EE, EE, DM_, PS_DM);
        const float* nw = (l + 1 < NL_) ? ln_w + (l + 1) * DM_ : fnorm_w;
        const float* nb = (l + 1 < NL_) ? ln_b + (l + 1) * DM_ : fnorm_b;
        reduce_ln_kernel<<<dim3(BL), blk, 0, stream>>>(
            h, hnb, parts, 4, PS_DM / 4, nullptr, nw, nb, 1);
    }

    // ---- out = hn @ op_w^T + op_b : partials x4 + fused bias reduce
    mgemm_kernel<5, 4, 0><<<dim3(DIN_ / 64, BL / 128, 4), blk, 0, stream>>>(
        parts, hnb, opwb, nullptr, DIN_, DM_ / 4, DM_, DM_, DIN_, (int)(BL * DIN_));
    reduce_bias_kernel<<<dim3((int)(BL * DIN_ / 4 + 255) / 256), blk, 0, stream>>>(
        out, parts, op_b, (int)(BL * DIN_ / 4), DIN_ / 4, (int)(BL * DIN_ / 4));
}

// Round 8
// 895.516 us; speedup vs baseline: 7.9197x; 1.0250x over previous
//
#include <hip/hip_runtime.h>
#include <math.h>

#define BB 2
#define LL 1024
#define DIN_ 512
#define DM_ 1024
#define NL_ 4
#define EE 2048
#define NN 16
#define RR 64
#define KK 4

#define NC 32   // scan chunks
#define CT 32   // timesteps per chunk (NC*CT == LL)

typedef unsigned short ushort_t;
typedef unsigned int uint_t;

using frag_ab = __attribute__((ext_vector_type(8))) short;
using frag_cd = __attribute__((ext_vector_type(4))) float;

__device__ __forceinline__ float softplus_f(float x) {
    return fmaxf(x, 0.f) + log1pf(expf(-fabsf(x)));
}
__device__ __forceinline__ float silu_fast(float x) {
    return x / (1.f + __expf(-x));
}
__device__ __forceinline__ float bf2f(ushort_t x) {
    return __uint_as_float((uint_t)x << 16);
}
__device__ __forceinline__ ushort_t f2bf(float x) {
    uint_t u = __float_as_uint(x);
    uint_t r = (u + 0x7fffu + ((u >> 16) & 1u)) >> 16;   // RNE
    return (ushort_t)r;
}
__device__ __forceinline__ void gload_lds16(const void* g, void* l) {
    __builtin_amdgcn_global_load_lds(
        (const __attribute__((address_space(1))) void*)g,
        (__attribute__((address_space(3))) void*)l, 16, 0, 0);
}

// ---------------------------------------------------------------------------
// Fused fp32 -> bf16 convert over 7 weight segments (1 launch).
// ---------------------------------------------------------------------------
struct CvtArgs {
    const float* src[7];
    ushort_t* dst[7];
    int cum[8];   // cumulative float4 counts; cum[0]=0
};

__global__ __launch_bounds__(256) void cvt_all_kernel(CvtArgs a)
{
    int i = blockIdx.x * 256 + threadIdx.x;
    if (i >= a.cum[7]) return;
    int s = 0;
#pragma unroll
    for (int k = 1; k < 7; k++) s += (i >= a.cum[k]) ? 1 : 0;
    int j = i - a.cum[s];
    float4 v = ((const float4*)a.src[s])[j];
    ushort4 u;
    u.x = f2bf(v.x); u.y = f2bf(v.y); u.z = f2bf(v.z); u.w = f2bf(v.w);
    ((ushort4*)a.dst[s])[j] = u;
}

// ---------------------------------------------------------------------------
// bf16 MFMA GEMM, BK=64 double-buffered staging, register-carried pointers.
// Tile M=128 x N=NT*16. 256 thr = 2x2 waves; wave = 4m x NT/2 n MFMA tiles.
// Unified LDS: smem[buf] holds (8+NT)*2 frags of 512 shorts; frag F=(G*2+kk)
// (G = m-frag 0..7 | 8+n-frag, kk = k-half). Staged via global_load_lds
// (uniform frag base + lane*16); read back as frag_ab at +lane*8 shorts.
// One __syncthreads per 64 k (32 MFMAs between barriers for NT=8).
// EPI: 0 none, 2 softplus(+bias), 5 split-K partial store (z -> Cf+z*pstride)
// ---------------------------------------------------------------------------
template <int EPI, int NT, int OUTBF>
__global__ __launch_bounds__(256) void mgemm_kernel(
    void* __restrict__ Cp, const ushort_t* __restrict__ A,
    const ushort_t* __restrict__ W, const float* __restrict__ bias,
    int N, int K, int lda, int ldw, int ldc, int pstride)
{
    __shared__ __attribute__((aligned(16))) ushort_t smem[2][(8 + NT) * 1024];

    const int tid = threadIdx.x;
    const int w = tid >> 6;
    const int lane = tid & 63;
    const int r = lane & 15;
    const int q = lane >> 4;
    const int m0 = blockIdx.y * 128;
    const int n0 = blockIdx.x * (NT * 16);
    const int wm = w >> 1;
    const int wn = w & 1;
    const int NWT = NT / 2;

    frag_cd acc[4][NWT];
#pragma unroll
    for (int i = 0; i < 4; i++)
#pragma unroll
        for (int j = 0; j < NWT; j++)
#pragma unroll
            for (int t = 0; t < 4; t++) acc[i][j][t] = 0.f;

    size_t koff = (EPI == 5) ? (size_t)blockIdx.z * K : 0;
    const ushort_t* Ab = A + (size_t)m0 * lda + koff;
    const ushort_t* Wb = W + (size_t)n0 * ldw + koff;

    // per-wave staging assignments: frag F = w + fi*4, F in [0, (8+NT)*2)
    constexpr int FPW = (8 + NT) * 2 / 4;
    const ushort_t* gp[FPW];
    bool ok[FPW];
#pragma unroll
    for (int fi = 0; fi < FPW; fi++) {
        int F = w + fi * 4;
        int kk = F & 1;
        int G = F >> 1;
        if (G < 8) {
            gp[fi] = Ab + (size_t)(G * 16 + r) * lda + kk * 32 + q * 8;
            ok[fi] = true;
        } else {
            int nt = G - 8;
            ok[fi] = (n0 + nt * 16 + r) < N;
            gp[fi] = Wb + (size_t)(nt * 16 + r) * ldw + kk * 32 + q * 8;
        }
    }

    auto stage = [&](int buf) {
#pragma unroll
        for (int fi = 0; fi < FPW; fi++) {
            if (ok[fi])
                gload_lds16(gp[fi], &smem[buf][(w + fi * 4) * 512]);
            gp[fi] += 64;   // advance one BK=64 tile
        }
    };

    stage(0);
    int buf = 0;
    for (int k0 = 0; k0 < K; k0 += 64) {
        __syncthreads();                       // drains staging into buf
        if (k0 + 64 < K) stage(buf ^ 1);       // async prefetch next tile
#pragma unroll
        for (int kk = 0; kk < 2; kk++) {
            frag_ab af[4], bf[NWT];
#pragma unroll
            for (int i = 0; i < 4; i++)
                af[i] = *(const frag_ab*)(&smem[buf][((wm * 4 + i) * 2 + kk) * 512] + lane * 8);
#pragma unroll
            for (int j = 0; j < NWT; j++)
                bf[j] = *(const frag_ab*)(&smem[buf][((8 + wn * NWT + j) * 2 + kk) * 512] + lane * 8);
#pragma unroll
            for (int i = 0; i < 4; i++)
#pragma unroll
                for (int j = 0; j < NWT; j++)
                    acc[i][j] = __builtin_amdgcn_mfma_f32_16x16x32_bf16(
                        af[i], bf[j], acc[i][j], 0, 0, 0);
        }
        buf ^= 1;
    }

    float* Cf = (float*)Cp;
    ushort_t* Cb = (ushort_t*)Cp;
    float* Cpart = (EPI == 5) ? Cf + (size_t)blockIdx.z * pstride : Cf;
#pragma unroll
    for (int i = 0; i < 4; i++) {
        int mrow = m0 + (wm * 4 + i) * 16 + q * 4;
#pragma unroll
        for (int j = 0; j < NWT; j++) {
            int col = n0 + (wn * NWT + j) * 16 + r;
            if (col >= N) continue;
            float bv = (EPI == 2) ? bias[col] : 0.f;
#pragma unroll
            for (int t = 0; t < 4; t++) {
                float v = acc[i][j][t];
                size_t idx = (size_t)(mrow + t) * ldc + col;
                if (EPI == 5) { Cpart[idx] = v; continue; }
                if (EPI == 2) v = softplus_f(v + bv);
                if (OUTBF) Cb[idx] = f2bf(v);
                else       Cf[idx] = v;
            }
        }
    }
}

// ---------------------------------------------------------------------------
// Fused split-K reduce + optional residual/bias + LayerNorm (D=1024).
// ---------------------------------------------------------------------------
__global__ __launch_bounds__(256) void reduce_ln_kernel(
    float* __restrict__ h, ushort_t* __restrict__ hn,
    const float* __restrict__ parts, int nparts, int pstride4,
    const float* __restrict__ bias,
    const float* __restrict__ w, const float* __restrict__ b, int hasres)
{
    const int row = blockIdx.x;
    const int tid = threadIdx.x;
    const int i4 = row * (DM_ / 4) + tid;

    float4 v = make_float4(0.f, 0.f, 0.f, 0.f);
    if (hasres) v = ((const float4*)h)[i4];
    for (int p = 0; p < nparts; p++) {
        float4 t = ((const float4*)parts)[(size_t)p * pstride4 + i4];
        v.x += t.x; v.y += t.y; v.z += t.z; v.w += t.w;
    }
    if (bias) {
        float4 t = ((const float4*)bias)[tid];
        v.x += t.x; v.y += t.y; v.z += t.z; v.w += t.w;
    }
    ((float4*)h)[i4] = v;

    float s = v.x + v.y + v.z + v.w;
    float sq = v.x * v.x + v.y * v.y + v.z * v.z + v.w * v.w;
#pragma unroll
    for (int off = 32; off; off >>= 1) {
        s += __shfl_down(s, off);
        sq += __shfl_down(sq, off);
    }
    __shared__ float ls[4], lq[4];
    int wid = tid >> 6;
    if ((tid & 63) == 0) { ls[wid] = s; lq[wid] = sq; }
    __syncthreads();
    float S = ls[0] + ls[1] + ls[2] + ls[3];
    float Q = lq[0] + lq[1] + lq[2] + lq[3];
    float mean = S * (1.f / DM_);
    float var = Q * (1.f / DM_) - mean * mean;
    float inv = rsqrtf(var + 1e-5f);
    float4 wv = ((const float4*)w)[tid];
    float4 bv = ((const float4*)b)[tid];
    ushort4 o;
    o.x = f2bf((v.x - mean) * inv * wv.x + bv.x);
    o.y = f2bf((v.y - mean) * inv * wv.y + bv.y);
    o.z = f2bf((v.z - mean) * inv * wv.z + bv.z);
    o.w = f2bf((v.w - mean) * inv * wv.w + bv.w);
    ((ushort4*)hn)[i4] = o;
}

// xdb = sum of 16 xproj partials; writes fp32 + bf16 copies.
__global__ __launch_bounds__(256) void reduce_xdb_kernel(
    float* __restrict__ xdb, ushort_t* __restrict__ xdbb,
    const float* __restrict__ parts, int pstride4, int total4)
{
    int i = blockIdx.x * 256 + threadIdx.x;
    if (i >= total4) return;
    float4 v = make_float4(0.f, 0.f, 0.f, 0.f);
#pragma unroll
    for (int p = 0; p < 16; p++) {
        float4 t = ((const float4*)parts)[(size_t)p * pstride4 + i];
        v.x += t.x; v.y += t.y; v.z += t.z; v.w += t.w;
    }
    ((float4*)xdb)[i] = v;
    ushort4 u;
    u.x = f2bf(v.x); u.y = f2bf(v.y); u.z = f2bf(v.z); u.w = f2bf(v.w);
    ((ushort4*)xdbb)[i] = u;
}

// out = sum of 4 partials + bias (final op projection)
__global__ __launch_bounds__(256) void reduce_bias_kernel(
    float* __restrict__ out, const float* __restrict__ parts,
    const float* __restrict__ bias, int pstride4, int n4, int total4)
{
    int i = blockIdx.x * 256 + threadIdx.x;
    if (i >= total4) return;
    float4 v = ((const float4*)bias)[i % n4];
#pragma unroll
    for (int p = 0; p < 4; p++) {
        float4 t = ((const float4*)parts)[(size_t)p * pstride4 + i];
        v.x += t.x; v.y += t.y; v.z += t.z; v.w += t.w;
    }
    ((float4*)out)[i] = v;
}

// ---------------------------------------------------------------------------
// Causal depthwise conv (K=4), 4 timesteps per thread.
// ---------------------------------------------------------------------------
__global__ __launch_bounds__(256) void conv_silu_kernel(
    ushort_t* __restrict__ xm, const ushort_t* __restrict__ xz,
    const float* __restrict__ cw, const float* __restrict__ cb)
{
    const int e = blockIdx.x * 256 + threadIdx.x;
    const int t0 = blockIdx.y * 4;
    const int b = blockIdx.z;
    const ushort_t* X = xz + (size_t)b * LL * 2 * EE + e;
    float4 w4 = ((const float4*)cw)[e];
    float wk[4] = {w4.x, w4.y, w4.z, w4.w};
    float cbv = cb[e];
    float v[7];
#pragma unroll
    for (int k = 0; k < 7; k++) {
        int t = t0 - 3 + k;
        v[k] = (t >= 0) ? bf2f(X[(size_t)t * 2 * EE]) : 0.f;
    }
    ushort_t* Y = xm + ((size_t)b * LL + t0) * EE + e;
#pragma unroll
    for (int j = 0; j < 4; j++) {
        float acc = cbv;
#pragma unroll
        for (int k = 0; k < 4; k++) acc = fmaf(wk[k], v[j + k], acc);
        Y[(size_t)j * EE] = f2bf(silu_fast(acc));
    }
}

// ---------------------------------------------------------------------------
// Thread-per-channel chunked scan (verified rounds 4-7).
// ---------------------------------------------------------------------------
__global__ __launch_bounds__(256) void scan_phase1_kernel(
    float* __restrict__ Pg, float* __restrict__ Sg,
    const float* __restrict__ dt, const ushort_t* __restrict__ u,
    const float* __restrict__ xdb, const float* __restrict__ A_log)
{
    const int tid = threadIdx.x;
    const int e = blockIdx.x * 256 + tid;
    const int c = blockIdx.y;
    const int b = blockIdx.z;
    const int t0 = c * CT;

    __shared__ float Bs[CT][16];
    {
        int tt = tid >> 3;
        int jj = tid & 7;
        if (jj < 4) {
            float4 v = *(const float4*)(xdb + ((size_t)(b * LL + t0 + tt) * 96 + 64 + jj * 4));
            *(float4*)&Bs[tt][jj * 4] = v;
        }
    }
    __syncthreads();

    float Ae[16];
#pragma unroll
    for (int k = 0; k < 4; k++) {
        float4 a = *(const float4*)(A_log + (size_t)e * NN + k * 4);
        Ae[k * 4 + 0] = -__expf(a.x);
        Ae[k * 4 + 1] = -__expf(a.y);
        Ae[k * 4 + 2] = -__expf(a.z);
        Ae[k * 4 + 3] = -__expf(a.w);
    }

    float S[16];
#pragma unroll
    for (int n = 0; n < 16; n++) S[n] = 0.f;
    float Dsum = 0.f;

    const float* dt_p = dt + (size_t)(b * LL + t0) * EE + e;
    const ushort_t* u_p = u + (size_t)(b * LL + t0) * EE + e;

    float dtv = dt_p[0];
    float uv = bf2f(u_p[0]);
#pragma unroll 4
    for (int i = 0; i < CT; i++) {
        int ip = (i + 1 < CT) ? i + 1 : i;
        float dtn = dt_p[(size_t)ip * EE];
        float un = bf2f(u_p[(size_t)ip * EE]);
        float dtu = dtv * uv;
        Dsum += dtv;
        float Bv[16];
#pragma unroll
        for (int k = 0; k < 4; k++)
            *(float4*)&Bv[k * 4] = *(const float4*)&Bs[i][k * 4];
#pragma unroll
        for (int n = 0; n < 16; n++) {
            float da = __expf(dtv * Ae[n]);
            S[n] = fmaf(da, S[n], dtu * Bv[n]);
        }
        dtv = dtn; uv = un;
    }

    size_t o = ((size_t)(b * NC + c) * EE + e) * 16;
#pragma unroll
    for (int k = 0; k < 4; k++) {
        float4 p4;
        p4.x = __expf(Dsum * Ae[k * 4 + 0]);
        p4.y = __expf(Dsum * Ae[k * 4 + 1]);
        p4.z = __expf(Dsum * Ae[k * 4 + 2]);
        p4.w = __expf(Dsum * Ae[k * 4 + 3]);
        *(float4*)(Pg + o + k * 4) = p4;
        *(float4*)(Sg + o + k * 4) = *(float4*)&S[k * 4];
    }
}

// Batched combine: load all 32 chunk summaries (independent, latency
// overlapped), register fma chain, independent stores.
__global__ __launch_bounds__(256) void scan_combine_kernel(
    float* __restrict__ Pg, const float* __restrict__ Sg)
{
    const int f = blockIdx.x * 256 + threadIdx.x;
    const int b = blockIdx.y;
    const size_t stride = (size_t)EE * 16;
    const size_t base = (size_t)b * NC * stride + f;

    float P[NC], S[NC];
#pragma unroll
    for (int c = 0; c < NC; c++) {
        P[c] = Pg[base + c * stride];
        S[c] = Sg[base + c * stride];
    }
    float h = 0.f;
#pragma unroll
    for (int c = 0; c < NC; c++) {
        h = fmaf(P[c], h, S[c]);
        P[c] = h;
    }
#pragma unroll
    for (int c = 0; c < NC; c++)
        Pg[base + c * stride] = P[c];
}

__global__ __launch_bounds__(256) void scan_phase2_kernel(
    ushort_t* __restrict__ y, const float* __restrict__ Pg,
    const float* __restrict__ dt, const ushort_t* __restrict__ u,
    const float* __restrict__ xdb, const ushort_t* __restrict__ xz,
    const float* __restrict__ A_log, const float* __restrict__ Dp)
{
    const int tid = threadIdx.x;
    const int e = blockIdx.x * 256 + tid;
    const int c = blockIdx.y;
    const int b = blockIdx.z;
    const int t0 = c * CT;

    __shared__ float Bs[CT][16], Cs[CT][16];
    {
        int tt = tid >> 3;
        int jj = tid & 7;
        float4 v = *(const float4*)(xdb + ((size_t)(b * LL + t0 + tt) * 96 + 64 + jj * 4));
        if (jj < 4) *(float4*)&Bs[tt][jj * 4] = v;
        else        *(float4*)&Cs[tt][(jj - 4) * 4] = v;
    }
    __syncthreads();

    float Ae[16];
#pragma unroll
    for (int k = 0; k < 4; k++) {
        float4 a = *(const float4*)(A_log + (size_t)e * NN + k * 4);
        Ae[k * 4 + 0] = -__expf(a.x);
        Ae[k * 4 + 1] = -__expf(a.y);
        Ae[k * 4 + 2] = -__expf(a.z);
        Ae[k * 4 + 3] = -__expf(a.w);
    }

    float h[16];
    if (c == 0) {
#pragma unroll
        for (int n = 0; n < 16; n++) h[n] = 0.f;
    } else {
        size_t o = ((size_t)(b * NC + (c - 1)) * EE + e) * 16;
#pragma unroll
        for (int k = 0; k < 4; k++)
            *(float4*)&h[k * 4] = *(const float4*)(Pg + o + k * 4);
    }

    const float Dv = Dp[e];
    const float* dt_p = dt + (size_t)(b * LL + t0) * EE + e;
    const ushort_t* u_p = u + (size_t)(b * LL + t0) * EE + e;
    const ushort_t* zg_p = xz + (size_t)(b * LL + t0) * 2 * EE + EE + e;
    ushort_t* y_p = y + (size_t)(b * LL + t0) * EE + e;

    float dtv = dt_p[0];
    float uv = bf2f(u_p[0]);
    float zv = bf2f(zg_p[0]);
#pragma unroll 4
    for (int i = 0; i < CT; i++) {
        int ip = (i + 1 < CT) ? i + 1 : i;
        float dtn = dt_p[(size_t)ip * EE];
        float un = bf2f(u_p[(size_t)ip * EE]);
        float zn = bf2f(zg_p[(size_t)ip * 2 * EE]);
        float dtu = dtv * uv;
        float Bv[16], Cv[16];
#pragma unroll
        for (int k = 0; k < 4; k++) {
            *(float4*)&Bv[k * 4] = *(const float4*)&Bs[i][k * 4];
            *(float4*)&Cv[k * 4] = *(const float4*)&Cs[i][k * 4];
        }
        float yv = 0.f;
#pragma unroll
        for (int n = 0; n < 16; n++) {
            float da = __expf(dtv * Ae[n]);
            h[n] = fmaf(da, h[n], dtu * Bv[n]);
            yv = fmaf(h[n], Cv[n], yv);
        }
        y_p[(size_t)i * EE] = f2bf((yv + uv * Dv) * silu_fast(zv));
        dtv = dtn; uv = un; zv = zn;
    }
}

// ---------------------------------------------------------------------------
extern "C" void kernel_launch(void* const* d_in, const int* in_sizes, int n_in,
                              void* d_out, int out_size, void* d_ws, size_t ws_size,
                              hipStream_t stream)
{
    const float* x = (const float*)d_in[0];
    const float* ip_w = (const float*)d_in[2];
    const float* ip_b = (const float*)d_in[3];
    const float* ln_w = (const float*)d_in[4];
    const float* ln_b = (const float*)d_in[5];
    const float* inproj_w = (const float*)d_in[6];
    const float* conv_w = (const float*)d_in[7];
    const float* conv_b = (const float*)d_in[8];
    const float* xproj_w = (const float*)d_in[9];
    const float* dtproj_w = (const float*)d_in[10];
    const float* dtproj_b = (const float*)d_in[11];
    const float* A_log = (const float*)d_in[12];
    const float* Dp = (const float*)d_in[13];
    const float* outproj_w = (const float*)d_in[14];
    const float* fnorm_w = (const float*)d_in[15];
    const float* fnorm_b = (const float*)d_in[16];
    const float* op_w = (const float*)d_in[17];
    const float* op_b = (const float*)d_in[18];
    float* out = (float*)d_out;

    const size_t BL = (size_t)BB * LL;   // 2048

    float* fp = (float*)d_ws;
    float* h = fp;           fp += BL * DM_;
    float* xdb = fp;         fp += BL * 96;
    float* dtb = fp;         fp += BL * EE;            // also: parts region base
    float* Pg = fp;          fp += (size_t)BB * NC * EE * 16;
    float* Sg = fp;          fp += (size_t)BB * NC * EE * 16;
    float* parts = dtb;      // overlay: dead whenever partials live
    ushort_t* us = (ushort_t*)fp;
    ushort_t* xb = us;       us += BL * DIN_;
    ushort_t* hnb = us;      us += BL * DM_;
    ushort_t* xzb = us;      us += BL * 2 * EE;
    ushort_t* xm = us;       us += BL * EE;
    ushort_t* xdbb = us;     us += BL * 96;
    ushort_t* yb = us;       us += BL * EE;
    ushort_t* ipwb = us;     us += (size_t)DM_ * DIN_;
    ushort_t* inprojb = us;  us += (size_t)NL_ * 2 * EE * DM_;
    ushort_t* xprojb = us;   us += (size_t)NL_ * 96 * EE;
    ushort_t* dtprojb = us;  us += (size_t)NL_ * EE * RR;
    ushort_t* outprojb = us; us += (size_t)NL_ * DM_ * EE;
    ushort_t* opwb = us;     us += (size_t)DIN_ * DM_;

    dim3 blk(256);

    // ---- single fused weight/input conversion
    {
        CvtArgs a;
        const float* srcs[7] = {x, ip_w, inproj_w, xproj_w, dtproj_w, outproj_w, op_w};
        ushort_t* dsts[7] = {xb, ipwb, inprojb, xprojb, dtprojb, outprojb, opwb};
        size_t ns[7] = {BL * DIN_, (size_t)DM_ * DIN_, (size_t)NL_ * 2 * EE * DM_,
                        (size_t)NL_ * 96 * EE, (size_t)NL_ * EE * RR,
                        (size_t)NL_ * DM_ * EE, (size_t)DIN_ * DM_};
        int cum = 0;
        for (int s = 0; s < 7; s++) {
            a.src[s] = srcs[s];
            a.dst[s] = dsts[s];
            a.cum[s] = cum;
            cum += (int)(ns[s] / 4);
        }
        a.cum[7] = cum;
        cvt_all_kernel<<<dim3((cum + 255) / 256), blk, 0, stream>>>(a);
    }

    const int PS_DM = (int)(BL * DM_);    // partial stride, DM-wide outputs

    // ---- ip: partials x2, then fused reduce(+ip_b) + LN[0]
    mgemm_kernel<5, 4, 0><<<dim3(DM_ / 64, BL / 128, 2), blk, 0, stream>>>(
        parts, xb, ipwb, nullptr, DM_, DIN_ / 2, DIN_, DIN_, DM_, PS_DM);
    reduce_ln_kernel<<<dim3(BL), blk, 0, stream>>>(
        h, hnb, parts, 2, PS_DM / 4, ip_b, ln_w, ln_b, 0);

    for (int l = 0; l < NL_; l++) {
        // xz = hn @ inproj^T (N=4096, K=1024), grid 512
        mgemm_kernel<0, 8, 1><<<dim3(2 * EE / 128, BL / 128), blk, 0, stream>>>(
            xzb, hnb, inprojb + (size_t)l * 2 * EE * DM_, nullptr,
            2 * EE, DM_, DM_, DM_, 2 * EE, 0);
        conv_silu_kernel<<<dim3(EE / 256, LL / 4, BB), blk, 0, stream>>>(
            xm, xzb, conv_w + l * EE * KK, conv_b + l * EE);
        // x_dbl partials x16 -> fused reduce (fp32 + bf16)
        mgemm_kernel<5, 8, 0><<<dim3(1, BL / 128, 16), blk, 0, stream>>>(
            parts, xm, xprojb + (size_t)l * 96 * EE, nullptr,
            96, EE / 16, EE, EE, 96, (int)(BL * 96));
        reduce_xdb_kernel<<<dim3((int)(BL * 96 / 4 + 255) / 256), blk, 0, stream>>>(
            xdb, xdbb, parts, (int)(BL * 96 / 4), (int)(BL * 96 / 4));
        // dt = softplus(x_dbl[:, :R] @ dtproj^T + b) (K=64)
        mgemm_kernel<2, 8, 0><<<dim3(EE / 128, BL / 128), blk, 0, stream>>>(
            dtb, xdbb, dtprojb + (size_t)l * EE * RR, dtproj_b + l * EE,
            EE, RR, 96, RR, EE, 0);

        scan_phase1_kernel<<<dim3(EE / 256, NC, BB), blk, 0, stream>>>(
            Pg, Sg, dtb, xm, xdb, A_log + (size_t)l * EE * NN);
        scan_combine_kernel<<<dim3(EE * 16 / 256, BB), blk, 0, stream>>>(Pg, Sg);
        scan_phase2_kernel<<<dim3(EE / 256, NC, BB), blk, 0, stream>>>(
            yb, Pg, dtb, xm, xdb, xzb, A_log + (size_t)l * EE * NN, Dp + l * EE);

        // outproj partials x4, then fused reduce + residual + next LN
        mgemm_kernel<5, 8, 0><<<dim3(DM_ / 128, BL / 128, 4), blk, 0, stream>>>(
            parts, yb, outprojb + (size_t)l * DM_ * EE, nullptr,
            DM_, EE / 4, EE, EE, DM_, PS_DM);
        const float* nw = (l + 1 < NL_) ? ln_w + (l + 1) * DM_ : fnorm_w;
        const float* nb = (l + 1 < NL_) ? ln_b + (l + 1) * DM_ : fnorm_b;
        reduce_ln_kernel<<<dim3(BL), blk, 0, stream>>>(
            h, hnb, parts, 4, PS_DM / 4, nullptr, nw, nb, 1);
    }

    // ---- out = hn @ op_w^T + op_b : partials x4 + fused bias reduce
    mgemm_kernel<5, 4, 0><<<dim3(DIN_ / 64, BL / 128, 4), blk, 0, stream>>>(
        parts, hnb, opwb, nullptr, DIN_, DM_ / 4, DM_, DM_, DIN_, (int)(BL * DIN_));
    reduce_bias_kernel<<<dim3((int)(BL * DIN_ / 4 + 255) / 256), blk, 0, stream>>>(
        out, parts, op_b, (int)(BL * DIN_ / 4), DIN_ / 4, (int)(BL * DIN_ / 4));
}